// Round 2
// baseline (130678.650 us; speedup 1.0000x reference)
//
#include <hip/hip_runtime.h>

// ---------------- problem dims ----------------
// B=32, T=512, E=512, TDEC=400, NMEL=80, RNN=1024, PRE=256, ADIM=128, KS=31
// outputs: mel [32][80][400] | gate [32][400] | align [32][400][512]
#define MEL_OFF   0
#define GATE_OFF  1024000
#define ALIGN_OFF 1036800

struct Ptrs {
  const float *mem, *dec, *Wpre1, *Wpre2, *WihA, *WhhA, *bihA, *bhhA,
              *WihD, *WhhD, *bihD, *bhhD, *Wq, *Wm, *Wsc, *bsc,
              *Wlc, *Wld, *Wproj, *bproj, *Wgate, *bgate;
  float *out;
  // workspace
  float *pm, *pre, *loc, *WqT, *Mc, *W2T, *W1T, *WmT, *p1;
  float *ah, *ahN, *dh, *dhN, *ac, *dc, *ctx, *aw, *awc, *esc, *den;
};

__device__ __forceinline__ float sigf(float x){
  return 1.f/(1.f+__expf(-fminf(fmaxf(x,-30.f),30.f)));
}
__device__ __forceinline__ float tanhfast(float x){
  float e = __expf(2.f*fminf(fmaxf(x,-15.f),15.f));
  return (e-1.f)/(e+1.f);
}

// ---------------- init: zero recurrent state ----------------
__global__ void k_init(float* p, int n){
  int i = blockIdx.x*256 + threadIdx.x;
  if (i < n) p[i] = 0.f;
}

// ---------------- transposes + collapsed location tensor ----------------
__global__ void k_xform(Ptrs P){
  int i = blockIdx.x*256 + threadIdx.x;
  if (i < 20480){ int k=i>>8, p=i&255; P.W1T[i] = P.Wpre1[p*80 + k]; return; }
  i -= 20480;
  if (i < 65536){ int k=i>>8, p=i&255; P.W2T[i] = P.Wpre2[p*256 + k]; return; }
  i -= 65536;
  if (i < 131072){ int k=i>>7, a=i&127; P.WqT[i] = P.Wq[a*1024 + k]; return; }
  i -= 131072;
  if (i < 65536){ int e=i>>7, a=i&127; P.WmT[i] = P.Wm[a*512 + e]; return; }
  i -= 65536;
  if (i < 7936){
    int c = i/3968, r = i%3968, k = r>>7, a = r&127;
    float s = 0.f;
    for (int f=0; f<31; f++) s += P.Wld[a*31+f]*P.Wlc[f*62 + c*31 + k];
    P.Mc[i] = s;
  }
}

// ---------------- prenet layer 1: p1 = relu(pin @ W1^T), rows = t*32+b ----------------
__global__ __launch_bounds__(256) void k_pn1(Ptrs P){
  __shared__ __align__(16) float pinL[8*80];
  int bid = blockIdx.x, tid = threadIdx.x;
  int r0 = bid*8;
  for (int i=tid; i<640; i+=256){
    int bi = i/80, m = i%80;
    int row = r0+bi, tt = row>>5, b = row&31;
    pinL[bi*80+m] = (tt==0) ? 0.f : P.dec[(size_t)b*32000 + m*400 + (tt-1)];
  }
  __syncthreads();
  int p = tid;
  float acc[8];
  #pragma unroll
  for (int bi=0;bi<8;bi++) acc[bi]=0.f;
  #pragma unroll
  for (int kq=0; kq<20; kq++){
    int k0 = kq*4;
    float w0 = P.W1T[(k0+0)*256+p], w1 = P.W1T[(k0+1)*256+p];
    float w2 = P.W1T[(k0+2)*256+p], w3 = P.W1T[(k0+3)*256+p];
    #pragma unroll
    for (int bi=0;bi<8;bi++){
      float4 x = *(float4*)(pinL + bi*80 + k0);
      acc[bi] += x.x*w0 + x.y*w1 + x.z*w2 + x.w*w3;
    }
  }
  #pragma unroll
  for (int bi=0;bi<8;bi++) P.p1[(size_t)(r0+bi)*256 + p] = fmaxf(acc[bi],0.f);
}

// ---------------- prenet layer 2: pre = relu(p1 @ W2^T) ----------------
__global__ __launch_bounds__(256) void k_pn2(Ptrs P){
  __shared__ __align__(16) float xL[8*256];
  int bid = blockIdx.x, tid = threadIdx.x;
  size_t r0 = (size_t)bid*8;
  for (int i4=tid; i4<512; i4+=256)
    *(float4*)(xL + i4*4) = *(const float4*)(P.p1 + r0*256 + i4*4);
  __syncthreads();
  int p = tid;
  float acc[8];
  #pragma unroll
  for (int bi=0;bi<8;bi++) acc[bi]=0.f;
  for (int kq=0; kq<64; kq++){
    int k0 = kq*4;
    float w0 = P.W2T[(k0+0)*256+p], w1 = P.W2T[(k0+1)*256+p];
    float w2 = P.W2T[(k0+2)*256+p], w3 = P.W2T[(k0+3)*256+p];
    #pragma unroll
    for (int bi=0;bi<8;bi++){
      float4 x = *(float4*)(xL + bi*256 + k0);
      acc[bi] += x.x*w0 + x.y*w1 + x.z*w2 + x.w*w3;
    }
  }
  #pragma unroll
  for (int bi=0;bi<8;bi++) P.pre[(r0+bi)*256 + p] = fmaxf(acc[bi],0.f);
}

// ---------------- processed_memory: pm[b,t,a] = mem[b,t,:]·Wm[a,:] ----------------
__global__ __launch_bounds__(256) void k_pm(Ptrs P){
  __shared__ __align__(16) float memL[8*512];
  int bid = blockIdx.x, tid = threadIdx.x;
  size_t r0 = (size_t)bid*8;            // flat (b,t) row
  for (int i4=tid; i4<1024; i4+=256)
    *(float4*)(memL + i4*4) = *(const float4*)(P.mem + r0*512 + i4*4);
  __syncthreads();
  int a = tid&127, rq = tid>>7;
  float acc[4];
  #pragma unroll
  for (int ri=0;ri<4;ri++) acc[ri]=0.f;
  for (int kq=0; kq<128; kq++){
    int k0 = kq*4;
    float w0 = P.WmT[(k0+0)*128+a], w1 = P.WmT[(k0+1)*128+a];
    float w2 = P.WmT[(k0+2)*128+a], w3 = P.WmT[(k0+3)*128+a];
    #pragma unroll
    for (int ri=0;ri<4;ri++){
      float4 x = *(float4*)(memL + (rq*4+ri)*512 + k0);
      acc[ri] += x.x*w0 + x.y*w1 + x.z*w2 + x.w*w3;
    }
  }
  #pragma unroll
  for (int ri=0;ri<4;ri++) P.pm[(r0 + rq*4+ri)*128 + a] = acc[ri];
}

// ---------------- k_A: att-LSTM + location-conv (this step) + projection (prev step) ----------------
__global__ __launch_bounds__(512) void k_A(Ptrs P, int t, int nAtt, int nConv, int nE){
  __shared__ float xs[16384];  // 64 KB
  int bid = blockIdx.x, tid = threadIdx.x;
  int wv = tid>>6, lane = tid&63;

  if (bid < nAtt){
    // ---- attention LSTM: x = [pre_t(256) | ctx(512) | ah(1024)], K=1792 ----
    if (bid==0 && tid<32) P.den[tid] = 0.f;   // reset softmax denom for this step
    int b0 = (bid&1)*16, j = (bid>>1)*8 + wv;
    float acc[64];
    #pragma unroll
    for (int i=0;i<64;i++) acc[i]=0.f;
    // phase A: k in [0,1024)
    for (int i4=tid; i4<4096; i4+=512){
      int bi = i4>>8; int kk = (i4&255)<<2;
      float4 v;
      if (kk < 256)      v = *(const float4*)(P.pre + (size_t)(t*32 + b0+bi)*256 + kk);
      else if (kk < 768) v = *(const float4*)(P.ctx + (b0+bi)*512 + (kk-256));
      else               v = *(const float4*)(P.ah  + (b0+bi)*1024 + (kk-768));
      *(float4*)(xs + bi*1024 + kk) = v;
    }
    __syncthreads();
    #pragma unroll
    for (int kq=0; kq<4; kq++){
      int k0 = kq*256 + lane*4;
      float4 xq[16];
      #pragma unroll
      for (int bi=0;bi<16;bi++) xq[bi] = *(float4*)(xs + bi*1024 + k0);
      #pragma unroll
      for (int g=0; g<4; g++){
        int row = g*1024 + j;
        float4 w4 = (kq<3) ? *(const float4*)(P.WihA + (size_t)row*768 + k0)
                           : *(const float4*)(P.WhhA + (size_t)row*1024 + (k0-768));
        #pragma unroll
        for (int bi=0;bi<16;bi++)
          acc[g*16+bi] += xq[bi].x*w4.x + xq[bi].y*w4.y + xq[bi].z*w4.z + xq[bi].w*w4.w;
      }
    }
    __syncthreads();
    // phase B: k in [1024,1792) -> ah[256+kk), view xs[16][768]
    for (int i4=tid; i4<3072; i4+=512){
      int bi = i4/192; int kk = (i4%192)<<2;
      *(float4*)(xs + bi*768 + kk) = *(const float4*)(P.ah + (b0+bi)*1024 + 256 + kk);
    }
    __syncthreads();
    #pragma unroll
    for (int kq=0; kq<3; kq++){
      int k0 = kq*256 + lane*4;
      float4 xq[16];
      #pragma unroll
      for (int bi=0;bi<16;bi++) xq[bi] = *(float4*)(xs + bi*768 + k0);
      #pragma unroll
      for (int g=0; g<4; g++){
        int row = g*1024 + j;
        float4 w4 = *(const float4*)(P.WhhA + (size_t)row*1024 + 256 + k0);
        #pragma unroll
        for (int bi=0;bi<16;bi++)
          acc[g*16+bi] += xq[bi].x*w4.x + xq[bi].y*w4.y + xq[bi].z*w4.z + xq[bi].w*w4.w;
      }
    }
    #pragma unroll
    for (int i=0;i<64;i++){
      float v = acc[i];
      #pragma unroll
      for (int d=1; d<64; d<<=1) v += __shfl_xor(v, d, 64);
      acc[i] = v;
    }
    float bsv[4];
    #pragma unroll
    for (int g=0;g<4;g++){ int row=g*1024+j; bsv[g] = P.bihA[row] + P.bhhA[row]; }
    #pragma unroll
    for (int bi=0;bi<16;bi++){
      float iv = sigf(acc[0*16+bi]+bsv[0]);
      float fv = sigf(acc[1*16+bi]+bsv[1]);
      float gv = tanhfast(acc[2*16+bi]+bsv[2]);
      float ov = sigf(acc[3*16+bi]+bsv[3]);
      float cp = P.ac[(b0+bi)*1024 + j];
      float c2 = fv*cp + iv*gv;
      float hh = ov*tanhfast(c2);
      if (lane==0){ P.ahN[(b0+bi)*1024+j] = hh; P.ac[(b0+bi)*1024+j] = c2; }
    }
  } else if (bid < nAtt+nConv){
    // ---- location conv (+pm pre-add): loc[b,t,a] = sum_{c,k} awcat[c,t+k-15]*Mc[c,k,a] + pm ----
    int gw = (bid-nAtt)*8 + wv;
    int b = gw>>6, rr = gw&63, t0 = (rr>>1)*16, a = (rr&1)*64 + lane;
    float awin[92];
    #pragma unroll
    for (int i=0;i<46;i++){
      int tt = t0-15+i;
      bool ok = (tt>=0) && (tt<512);
      awin[i]    = ok ? P.aw [b*512+tt] : 0.f;
      awin[46+i] = ok ? P.awc[b*512+tt] : 0.f;
    }
    float acc[16];
    #pragma unroll
    for (int tl=0;tl<16;tl++) acc[tl]=0.f;
    #pragma unroll
    for (int c=0;c<2;c++){
      #pragma unroll
      for (int k=0;k<31;k++){
        float mcv = P.Mc[(c*31+k)*128 + a];
        #pragma unroll
        for (int tl=0;tl<16;tl++) acc[tl] += awin[c*46 + tl + k]*mcv;
      }
    }
    #pragma unroll
    for (int tl=0;tl<16;tl++){
      size_t idx = ((size_t)b*512 + t0+tl)*128 + a;
      P.loc[idx] = acc[tl] + P.pm[idx];
    }
  } else {
    // ---- projection for step t-1: x = [dh(1024) | ctx(512)], rows 0..79 mel, 80 gate ----
    int eb = bid - nAtt - nConv;
    int b0 = (eb&1)*16;
    int row = (eb>>1)*8 + wv;
    bool act = (row <= 80);
    const float* wrow = (row<80) ? (P.Wproj + (size_t)row*1536) : P.Wgate;
    float acc[16];
    #pragma unroll
    for (int bi=0;bi<16;bi++) acc[bi]=0.f;
    for (int i4=tid; i4<4096; i4+=512){
      int bi=i4>>8, kk=(i4&255)<<2;
      *(float4*)(xs + bi*1024 + kk) = *(const float4*)(P.dh + (b0+bi)*1024 + kk);
    }
    __syncthreads();
    if (act){
      #pragma unroll
      for (int kq=0;kq<4;kq++){
        int k0=kq*256+lane*4;
        float4 w4 = *(const float4*)(wrow + k0);
        #pragma unroll
        for (int bi=0;bi<16;bi++){
          float4 x = *(float4*)(xs + bi*1024 + k0);
          acc[bi] += x.x*w4.x + x.y*w4.y + x.z*w4.z + x.w*w4.w;
        }
      }
    }
    __syncthreads();
    for (int i4=tid; i4<2048; i4+=512){
      int bi=i4>>7, kk=(i4&127)<<2;
      *(float4*)(xs + bi*512 + kk) = *(const float4*)(P.ctx + (b0+bi)*512 + kk);
    }
    __syncthreads();
    if (act){
      #pragma unroll
      for (int kq=0;kq<2;kq++){
        int k0=kq*256+lane*4;
        float4 w4 = *(const float4*)(wrow + 1024 + k0);
        #pragma unroll
        for (int bi=0;bi<16;bi++){
          float4 x = *(float4*)(xs + bi*512 + k0);
          acc[bi] += x.x*w4.x + x.y*w4.y + x.z*w4.z + x.w*w4.w;
        }
      }
      #pragma unroll
      for (int bi=0;bi<16;bi++){
        float v = acc[bi];
        #pragma unroll
        for (int d=1; d<64; d<<=1) v += __shfl_xor(v, d, 64);
        acc[bi]=v;
      }
      if (lane==0){
        float bias = (row<80)? P.bproj[row] : P.bgate[0];
        #pragma unroll
        for (int bi=0;bi<16;bi++){
          float v = acc[bi]+bias;
          if (row<80) P.out[(size_t)(b0+bi)*32000 + row*400 + (t-1)] = v;
          else        P.out[GATE_OFF + (b0+bi)*400 + (t-1)] = v;
        }
      }
    }
  }
}

// ---------------- k_B: q = ah@Wq^T, scores, exp, denom; also zero ctx ----------------
__global__ __launch_bounds__(512) void k_B(Ptrs P){
  __shared__ __align__(16) float ahL[1024];
  __shared__ __align__(16) float qp[4*128];
  __shared__ __align__(16) float qL[128];
  int bid = blockIdx.x, tid = threadIdx.x;
  int b = bid>>1, h = bid&1;
  if (tid < 256) P.ctx[b*512 + h*256 + tid] = 0.f;
  for (int i=tid; i<1024; i+=512) ahL[i] = P.ahN[b*1024 + i];
  __syncthreads();
  {
    int a = tid&127, kq = tid>>7;
    float p = 0.f;
    for (int k2=0; k2<256; k2+=4){
      int k = kq*256 + k2;
      float4 av = *(float4*)(ahL + k);
      p += av.x*P.WqT[(k+0)*128+a] + av.y*P.WqT[(k+1)*128+a]
         + av.z*P.WqT[(k+2)*128+a] + av.w*P.WqT[(k+3)*128+a];
    }
    qp[kq*128 + a] = p;
  }
  __syncthreads();
  if (tid < 128) qL[tid] = qp[tid] + qp[128+tid] + qp[256+tid] + qp[384+tid];
  __syncthreads();
  int tl = tid>>1, ha = tid&1, s = h*256 + tl;
  const float* base = P.loc + ((size_t)b*512 + s)*128 + ha*64;   // loc already includes pm
  const float* wsp = P.Wsc + ha*64;
  const float* qb  = qL + ha*64;
  float p = 0.f;
  #pragma unroll
  for (int i=0;i<64;i+=4){
    float4 lv = *(const float4*)(base+i);
    float4 wv = *(const float4*)(wsp+i);
    float4 qv = *(const float4*)(qb+i);
    p += wv.x*tanhfast(qv.x+lv.x) + wv.y*tanhfast(qv.y+lv.y)
       + wv.z*tanhfast(qv.z+lv.z) + wv.w*tanhfast(qv.w+lv.w);
  }
  p += __shfl_xor(p, 1, 64);
  float ex = 0.f;
  if (ha == 0){
    float sc = p + P.bsc[0];         // |sc| <= ~2.1 (tanh-bounded): exp safe w/o max-sub
    ex = __expf(sc);
    P.esc[b*512 + s] = ex;
  }
  #pragma unroll
  for (int d=1; d<64; d<<=1) ex += __shfl_xor(ex, d, 64);
  if ((tid&63)==0) atomicAdd(&P.den[b], ex);
}

// ---------------- k_C: normalize w, alignments out, awcum, ctx = w·memory ----------------
__global__ __launch_bounds__(512) void k_C(Ptrs P, int t){
  __shared__ __align__(16) float wL[128];
  int bid = blockIdx.x, tid = threadIdx.x;
  int b = bid>>2, sb = bid&3, s0 = sb*128;
  if (tid < 128){
    int s = s0 + tid;
    float w = P.esc[b*512+s] / P.den[b];
    P.aw[b*512+s] = w;
    P.awc[b*512+s] += w;
    P.out[ALIGN_OFF + (size_t)b*204800 + (size_t)t*512 + s] = w;
    wL[tid] = w;
  }
  __syncthreads();
  int e = tid;
  float acc = 0.f;
  for (int i=0;i<128;i+=4){
    float4 wv = *(float4*)(wL + i);
    const float* mrow = P.mem + ((size_t)b*512 + s0+i)*512 + e;
    acc += wv.x*mrow[0] + wv.y*mrow[512] + wv.z*mrow[1024] + wv.w*mrow[1536];
  }
  atomicAdd(&P.ctx[b*512 + e], acc);
}

// ---------------- k_D: decoder LSTM: x = [ah_t(1024) | ctx_t(512) | dh(1024)], K=2560 ----------------
__global__ __launch_bounds__(512) void k_D(Ptrs P){
  __shared__ float xs[16384];
  int bid = blockIdx.x, tid = threadIdx.x;
  int wv = tid>>6, lane = tid&63;
  int b0 = (bid&1)*16, j = (bid>>1)*8 + wv;
  float acc[64];
  #pragma unroll
  for (int i=0;i<64;i++) acc[i]=0.f;
  // P1: k in [0,1024): ah_t
  for (int i4=tid; i4<4096; i4+=512){
    int bi=i4>>8, kk=(i4&255)<<2;
    *(float4*)(xs + bi*1024 + kk) = *(const float4*)(P.ahN + (b0+bi)*1024 + kk);
  }
  __syncthreads();
  #pragma unroll
  for (int kq=0; kq<4; kq++){
    int k0 = kq*256 + lane*4;
    float4 xq[16];
    #pragma unroll
    for (int bi=0;bi<16;bi++) xq[bi] = *(float4*)(xs + bi*1024 + k0);
    #pragma unroll
    for (int g=0; g<4; g++){
      int row = g*1024 + j;
      float4 w4 = *(const float4*)(P.WihD + (size_t)row*1536 + k0);
      #pragma unroll
      for (int bi=0;bi<16;bi++)
        acc[g*16+bi] += xq[bi].x*w4.x + xq[bi].y*w4.y + xq[bi].z*w4.z + xq[bi].w*w4.w;
    }
  }
  __syncthreads();
  // P2: k in [1024,2048): ctx (first 512), dh (next 512)
  for (int i4=tid; i4<4096; i4+=512){
    int bi=i4>>8, kk=(i4&255)<<2;
    float4 v = (kk < 512) ? *(const float4*)(P.ctx + (b0+bi)*512 + kk)
                          : *(const float4*)(P.dh  + (b0+bi)*1024 + (kk-512));
    *(float4*)(xs + bi*1024 + kk) = v;
  }
  __syncthreads();
  #pragma unroll
  for (int kq=0; kq<4; kq++){
    int k0 = kq*256 + lane*4;
    float4 xq[16];
    #pragma unroll
    for (int bi=0;bi<16;bi++) xq[bi] = *(float4*)(xs + bi*1024 + k0);
    #pragma unroll
    for (int g=0; g<4; g++){
      int row = g*1024 + j;
      float4 w4 = (kq<2) ? *(const float4*)(P.WihD + (size_t)row*1536 + 1024 + k0)
                         : *(const float4*)(P.WhhD + (size_t)row*1024 + (k0-512));
      #pragma unroll
      for (int bi=0;bi<16;bi++)
        acc[g*16+bi] += xq[bi].x*w4.x + xq[bi].y*w4.y + xq[bi].z*w4.z + xq[bi].w*w4.w;
    }
  }
  __syncthreads();
  // P3: k in [2048,2560): dh[512+kk)
  for (int i4=tid; i4<2048; i4+=512){
    int bi=i4>>7, kk=(i4&127)<<2;
    *(float4*)(xs + bi*512 + kk) = *(const float4*)(P.dh + (b0+bi)*1024 + 512 + kk);
  }
  __syncthreads();
  #pragma unroll
  for (int kq=0; kq<2; kq++){
    int k0 = kq*256 + lane*4;
    float4 xq[16];
    #pragma unroll
    for (int bi=0;bi<16;bi++) xq[bi] = *(float4*)(xs + bi*512 + k0);
    #pragma unroll
    for (int g=0; g<4; g++){
      int row = g*1024 + j;
      float4 w4 = *(const float4*)(P.WhhD + (size_t)row*1024 + 512 + k0);
      #pragma unroll
      for (int bi=0;bi<16;bi++)
        acc[g*16+bi] += xq[bi].x*w4.x + xq[bi].y*w4.y + xq[bi].z*w4.z + xq[bi].w*w4.w;
    }
  }
  #pragma unroll
  for (int i=0;i<64;i++){
    float v = acc[i];
    #pragma unroll
    for (int d=1; d<64; d<<=1) v += __shfl_xor(v, d, 64);
    acc[i] = v;
  }
  float bsv[4];
  #pragma unroll
  for (int g=0;g<4;g++){ int row=g*1024+j; bsv[g] = P.bihD[row] + P.bhhD[row]; }
  #pragma unroll
  for (int bi=0;bi<16;bi++){
    float iv = sigf(acc[0*16+bi]+bsv[0]);
    float fv = sigf(acc[1*16+bi]+bsv[1]);
    float gv = tanhfast(acc[2*16+bi]+bsv[2]);
    float ov = sigf(acc[3*16+bi]+bsv[3]);
    float cp = P.dc[(b0+bi)*1024 + j];
    float c2 = fv*cp + iv*gv;
    float hh = ov*tanhfast(c2);
    if (lane==0){ P.dhN[(b0+bi)*1024+j] = hh; P.dc[(b0+bi)*1024+j] = c2; }
  }
}

// ---------------- host ----------------
extern "C" void kernel_launch(void* const* d_in, const int* in_sizes, int n_in,
                              void* d_out, int out_size, void* d_ws, size_t ws_size,
                              hipStream_t stream) {
  Ptrs P;
  P.mem   = (const float*)d_in[0];  P.dec   = (const float*)d_in[1];
  P.Wpre1 = (const float*)d_in[2];  P.Wpre2 = (const float*)d_in[3];
  P.WihA  = (const float*)d_in[4];  P.WhhA  = (const float*)d_in[5];
  P.bihA  = (const float*)d_in[6];  P.bhhA  = (const float*)d_in[7];
  P.WihD  = (const float*)d_in[8];  P.WhhD  = (const float*)d_in[9];
  P.bihD  = (const float*)d_in[10]; P.bhhD  = (const float*)d_in[11];
  P.Wq    = (const float*)d_in[12]; P.Wm    = (const float*)d_in[13];
  P.Wsc   = (const float*)d_in[14]; P.bsc   = (const float*)d_in[15];
  P.Wlc   = (const float*)d_in[16]; P.Wld   = (const float*)d_in[17];
  P.Wproj = (const float*)d_in[18]; P.bproj = (const float*)d_in[19];
  P.Wgate = (const float*)d_in[20]; P.bgate = (const float*)d_in[21];
  P.out = (float*)d_out;

  float* ws = (float*)d_ws;
  size_t o = 0;
  P.pm  = ws + o; o += 2097152;      // [32][512][128]
  P.pre = ws + o; o += 3276800;      // [400][32][256]
  P.loc = ws + o; o += 2097152;      // [32][512][128]  (loc + pm)
  P.WqT = ws + o; o += 131072;
  P.Mc  = ws + o; o += 7936;
  P.W2T = ws + o; o += 65536;
  P.W1T = ws + o; o += 20480;
  P.WmT = ws + o; o += 65536;
  P.p1  = ws + o; o += 3276800;
  float* stateBase = ws + o;
  float* AH[2]; AH[0] = ws + o; o += 32768; AH[1] = ws + o; o += 32768;
  float* DH[2]; DH[0] = ws + o; o += 32768; DH[1] = ws + o; o += 32768;
  P.ac  = ws + o; o += 32768;
  P.dc  = ws + o; o += 32768;
  P.ctx = ws + o; o += 16384;
  P.aw  = ws + o; o += 16384;
  P.awc = ws + o; o += 16384;
  P.esc = ws + o; o += 16384;
  P.den = ws + o; o += 32;
  int stateN = (int)((ws + o) - stateBase);

  hipLaunchKernelGGL(k_init, dim3((stateN+255)/256), dim3(256), 0, stream, stateBase, stateN);
  P.ah = AH[0]; P.ahN = AH[1]; P.dh = DH[0]; P.dhN = DH[1];
  hipLaunchKernelGGL(k_xform, dim3(1135), dim3(256), 0, stream, P);
  hipLaunchKernelGGL(k_pn1, dim3(1600), dim3(256), 0, stream, P);
  hipLaunchKernelGGL(k_pn2, dim3(1600), dim3(256), 0, stream, P);
  hipLaunchKernelGGL(k_pm,  dim3(2048), dim3(256), 0, stream, P);

  for (int t=0; t<400; t++){
    Ptrs Q = P;
    Q.ah  = AH[t&1];     Q.ahN = AH[(t+1)&1];
    Q.dh  = DH[t&1];     Q.dhN = DH[(t+1)&1];
    int nE = t ? 22 : 0;
    hipLaunchKernelGGL(k_A, dim3(512+nE), dim3(512), 0, stream, Q, t, 256, 256, nE);
    hipLaunchKernelGGL(k_B, dim3(64),  dim3(512), 0, stream, Q);
    hipLaunchKernelGGL(k_C, dim3(128), dim3(512), 0, stream, Q, t);
    hipLaunchKernelGGL(k_D, dim3(256), dim3(512), 0, stream, Q);
  }
  // final projection for step 399
  Ptrs Q = P;
  Q.ah = AH[0]; Q.ahN = AH[1];
  Q.dh = DH[0]; Q.dhN = DH[1];   // DH[0] holds dh_399 (written at t=399)
  hipLaunchKernelGGL(k_A, dim3(22), dim3(512), 0, stream, Q, 400, 0, 0, 22);
}

// Round 4
// 47668.976 us; speedup vs baseline: 2.7414x; 2.7414x over previous
//
#include <hip/hip_runtime.h>

// B=32, T=512, E=512, TDEC=400, NMEL=80, RNN=1024, PRE=256, ADIM=128, KS=31
// outputs: mel [32][80][400] | gate [32][400] | align [32][400][512]
#define GATE_OFF  1024000
#define ALIGN_OFF 1036800

struct Ptrs {
  const float *mem, *dec, *Wpre1, *Wpre2, *WihA, *WhhA, *bihA, *bhhA,
              *WihD, *WhhD, *bihD, *bhhD, *Wq, *Wm, *Wsc, *bsc,
              *Wlc, *Wld, *Wproj, *bproj, *Wgate, *bgate;
  float *out;
  // workspace
  float *pm, *pre, *loc, *WqT, *Mc, *W1T, *W2T, *WmT, *p1, *WAT, *WDT, *gpA, *gpD;
  float *ahp, *ahn, *acp, *acn, *dh, *dc, *ctxP, *ctxN, *aw, *awc, *esc, *den;
};

__device__ __forceinline__ float rcpf(float x){ return __builtin_amdgcn_rcpf(x); }
__device__ __forceinline__ float sigf(float x){
  x = fminf(fmaxf(x,-30.f),30.f);
  return rcpf(1.f+__expf(-x));
}
__device__ __forceinline__ float tanhfast(float x){
  x = fminf(fmaxf(x,-15.f),15.f);
  float e = __expf(2.f*x);
  return (e-1.f)*rcpf(e+1.f);
}

// ---------------- init: zero recurrent state ----------------
__global__ void k_init(float* p, int n){
  int i = blockIdx.x*256 + threadIdx.x;
  if (i < n) p[i] = 0.f;
}

// ---------------- small transposes + collapsed location tensor ----------------
__global__ void k_xform(Ptrs P){
  int i = blockIdx.x*256 + threadIdx.x;
  if (i < 20480){ int k=i>>8, p=i&255; P.W1T[i] = P.Wpre1[p*80 + k]; return; }
  i -= 20480;
  if (i < 65536){ int k=i>>8, p=i&255; P.W2T[i] = P.Wpre2[p*256 + k]; return; }
  i -= 65536;
  if (i < 131072){ int k=i>>7, a=i&127; P.WqT[i] = P.Wq[a*1024 + k]; return; }
  i -= 131072;
  if (i < 65536){ int e=i>>7, a=i&127; P.WmT[i] = P.Wm[a*512 + e]; return; }
  i -= 65536;
  if (i < 7936){
    int c = i/3968, r = i%3968, k = r>>7, a = r&127;
    float s = 0.f;
    for (int f=0; f<31; f++) s += P.Wld[a*31+f]*P.Wlc[f*62 + c*31 + k];
    P.Mc[i] = s;
  }
}

// ---------------- big weight transposes (tiled): WAT[k][4096], WDT[k][4096] ----------------
__global__ __launch_bounds__(256) void k_tA(Ptrs P){
  __shared__ float tb[32][33];
  int bid = blockIdx.x, tid = threadIdx.x;
  int jt = bid/56, kt = bid%56;
  int j0 = jt*32, k0 = kt*32;
  int r = tid>>3, s = tid&7;
  const float* src; int ld, kk0;
  if (k0 < 768){ src = P.WihA; ld = 768;  kk0 = k0; }
  else         { src = P.WhhA; ld = 1024; kk0 = k0-768; }
  float4 v = *(const float4*)(src + (size_t)(j0+r)*ld + kk0 + s*4);
  tb[r][s*4+0]=v.x; tb[r][s*4+1]=v.y; tb[r][s*4+2]=v.z; tb[r][s*4+3]=v.w;
  __syncthreads();
  float4 o2; o2.x=tb[s*4+0][r]; o2.y=tb[s*4+1][r]; o2.z=tb[s*4+2][r]; o2.w=tb[s*4+3][r];
  *(float4*)(P.WAT + (size_t)(k0+r)*4096 + j0 + s*4) = o2;
}
__global__ __launch_bounds__(256) void k_tD(Ptrs P){
  __shared__ float tb[32][33];
  int bid = blockIdx.x, tid = threadIdx.x;
  int jt = bid/80, kt = bid%80;
  int j0 = jt*32, k0 = kt*32;
  int r = tid>>3, s = tid&7;
  const float* src; int ld, kk0;
  if (k0 < 1536){ src = P.WihD; ld = 1536; kk0 = k0; }
  else          { src = P.WhhD; ld = 1024; kk0 = k0-1536; }
  float4 v = *(const float4*)(src + (size_t)(j0+r)*ld + kk0 + s*4);
  tb[r][s*4+0]=v.x; tb[r][s*4+1]=v.y; tb[r][s*4+2]=v.z; tb[r][s*4+3]=v.w;
  __syncthreads();
  float4 o2; o2.x=tb[s*4+0][r]; o2.y=tb[s*4+1][r]; o2.z=tb[s*4+2][r]; o2.w=tb[s*4+3][r];
  *(float4*)(P.WDT + (size_t)(k0+r)*4096 + j0 + s*4) = o2;
}

// ---------------- prenet layer 1 ----------------
__global__ __launch_bounds__(256) void k_pn1(Ptrs P){
  __shared__ __align__(16) float pinL[8*80];
  int bid = blockIdx.x, tid = threadIdx.x;
  int r0 = bid*8;
  for (int i=tid; i<640; i+=256){
    int bi = i/80, m = i%80;
    int row = r0+bi, tt = row>>5, b = row&31;
    pinL[bi*80+m] = (tt==0) ? 0.f : P.dec[(size_t)b*32000 + m*400 + (tt-1)];
  }
  __syncthreads();
  int p = tid;
  float acc[8];
  #pragma unroll
  for (int bi=0;bi<8;bi++) acc[bi]=0.f;
  #pragma unroll
  for (int kq=0; kq<20; kq++){
    int k0 = kq*4;
    float w0 = P.W1T[(k0+0)*256+p], w1 = P.W1T[(k0+1)*256+p];
    float w2 = P.W1T[(k0+2)*256+p], w3 = P.W1T[(k0+3)*256+p];
    #pragma unroll
    for (int bi=0;bi<8;bi++){
      float4 x = *(float4*)(pinL + bi*80 + k0);
      acc[bi] += x.x*w0 + x.y*w1 + x.z*w2 + x.w*w3;
    }
  }
  #pragma unroll
  for (int bi=0;bi<8;bi++) P.p1[(size_t)(r0+bi)*256 + p] = fmaxf(acc[bi],0.f);
}

// ---------------- prenet layer 2 ----------------
__global__ __launch_bounds__(256) void k_pn2(Ptrs P){
  __shared__ __align__(16) float xL[8*256];
  int bid = blockIdx.x, tid = threadIdx.x;
  size_t r0 = (size_t)bid*8;
  for (int i4=tid; i4<512; i4+=256)
    *(float4*)(xL + i4*4) = *(const float4*)(P.p1 + r0*256 + i4*4);
  __syncthreads();
  int p = tid;
  float acc[8];
  #pragma unroll
  for (int bi=0;bi<8;bi++) acc[bi]=0.f;
  for (int kq=0; kq<64; kq++){
    int k0 = kq*4;
    float w0 = P.W2T[(k0+0)*256+p], w1 = P.W2T[(k0+1)*256+p];
    float w2 = P.W2T[(k0+2)*256+p], w3 = P.W2T[(k0+3)*256+p];
    #pragma unroll
    for (int bi=0;bi<8;bi++){
      float4 x = *(float4*)(xL + bi*256 + k0);
      acc[bi] += x.x*w0 + x.y*w1 + x.z*w2 + x.w*w3;
    }
  }
  #pragma unroll
  for (int bi=0;bi<8;bi++) P.pre[(r0+bi)*256 + p] = fmaxf(acc[bi],0.f);
}

// ---------------- processed_memory ----------------
__global__ __launch_bounds__(256) void k_pm(Ptrs P){
  __shared__ __align__(16) float memL[8*512];
  int bid = blockIdx.x, tid = threadIdx.x;
  size_t r0 = (size_t)bid*8;
  for (int i4=tid; i4<1024; i4+=256)
    *(float4*)(memL + i4*4) = *(const float4*)(P.mem + r0*512 + i4*4);
  __syncthreads();
  int a = tid&127, rq = tid>>7;
  float acc[4];
  #pragma unroll
  for (int ri=0;ri<4;ri++) acc[ri]=0.f;
  for (int kq=0; kq<128; kq++){
    int k0 = kq*4;
    float w0 = P.WmT[(k0+0)*128+a], w1 = P.WmT[(k0+1)*128+a];
    float w2 = P.WmT[(k0+2)*128+a], w3 = P.WmT[(k0+3)*128+a];
    #pragma unroll
    for (int ri=0;ri<4;ri++){
      float4 x = *(float4*)(memL + (rq*4+ri)*512 + k0);
      acc[ri] += x.x*w0 + x.y*w1 + x.z*w2 + x.w*w3;
    }
  }
  #pragma unroll
  for (int ri=0;ri<4;ri++) P.pm[(r0 + rq*4+ri)*128 + a] = acc[ri];
}

// ---------------- k_A: att-GEMM partials + location-conv + dec-activation(t-1) ----------------
__global__ __launch_bounds__(512) void k_A(Ptrs P, int t, int nG, int nConv, int nActD){
  __shared__ float sm[16640];   // gemm reduce: [w:8][b:32][65]
  int bid = blockIdx.x, tid = threadIdx.x;
  int w = tid>>6, lane = tid&63;

  if (bid < nG){
    if (bid==0 && tid<32) P.den[tid] = 0.f;
    int jt = bid>>2, c = bid&3;
    int j = jt*64 + lane;
    int kbase = c*448 + w*56;
    float acc[32];
    #pragma unroll
    for (int b=0;b<32;b++) acc[b]=0.f;
    for (int kt=0; kt<7; kt++){
      int k0 = kbase + kt*8;
      float wv[8];
      #pragma unroll
      for (int u=0;u<8;u++) wv[u] = P.WAT[(size_t)(k0+u)*4096 + j];
      const float* xb; int ld;
      if (k0 < 256){      xb = P.pre + ((size_t)t*32)*256 + k0; ld = 256; }
      else if (k0 < 768){ xb = P.ctxP + (k0-256);               ld = 512; }
      else{               xb = P.ahp + (k0-768);                ld = 1024; }
      #pragma unroll
      for (int b=0;b<32;b++){
        #pragma unroll
        for (int u=0;u<8;u++) acc[b] += wv[u]*xb[u];
        xb += ld;
      }
    }
    #pragma unroll
    for (int b=0;b<32;b++) sm[(w*32+b)*65 + lane] = acc[b];
    __syncthreads();
    #pragma unroll
    for (int i=0;i<4;i++){
      int o = tid + i*512;
      int j2 = o&63, b = o>>6;
      float s = 0.f;
      #pragma unroll
      for (int w2=0;w2<8;w2++) s += sm[(w2*32+b)*65 + j2];
      P.gpA[(size_t)(c*32+b)*4096 + jt*64 + j2] = s;
    }
  } else if (bid < nG+nConv){
    // location conv (+pm pre-add)
    int gw = (bid-nG)*8 + w;
    int b = gw>>6, rr = gw&63, t0 = (rr>>1)*16, a = (rr&1)*64 + lane;
    float awin[92];
    #pragma unroll
    for (int i=0;i<46;i++){
      int tt = t0-15+i;
      bool ok = (tt>=0) && (tt<512);
      awin[i]    = ok ? P.aw [b*512+tt] : 0.f;
      awin[46+i] = ok ? P.awc[b*512+tt] : 0.f;
    }
    float acc[16];
    #pragma unroll
    for (int tl=0;tl<16;tl++) acc[tl]=0.f;
    #pragma unroll
    for (int c=0;c<2;c++){
      #pragma unroll
      for (int k=0;k<31;k++){
        float mcv = P.Mc[(c*31+k)*128 + a];
        #pragma unroll
        for (int tl=0;tl<16;tl++) acc[tl] += awin[c*46 + tl + k]*mcv;
      }
    }
    #pragma unroll
    for (int tl=0;tl<16;tl++){
      size_t idx = ((size_t)b*512 + t0+tl)*128 + a;
      P.loc[idx] = acc[tl] + P.pm[idx];
    }
  } else {
    // dec activation for step t-1: reduce gpD partials -> dh, dc
    int b = bid - nG - nConv;   // 0..31
    #pragma unroll
    for (int i=0;i<2;i++){
      int jj = tid + i*512;
      float gi=0.f, gf=0.f, gg=0.f, go=0.f;
      #pragma unroll
      for (int c=0;c<4;c++){
        const float* g = P.gpD + (size_t)(c*32+b)*4096;
        gi += g[jj]; gf += g[1024+jj]; gg += g[2048+jj]; go += g[3072+jj];
      }
      gi += P.bihD[jj]      + P.bhhD[jj];
      gf += P.bihD[1024+jj] + P.bhhD[1024+jj];
      gg += P.bihD[2048+jj] + P.bhhD[2048+jj];
      go += P.bihD[3072+jj] + P.bhhD[3072+jj];
      float c2 = sigf(gf)*P.dc[b*1024+jj] + sigf(gi)*tanhfast(gg);
      float hh = sigf(go)*tanhfast(c2);
      P.dc[b*1024+jj] = c2;
      P.dh[b*1024+jj] = hh;
    }
  }
}

// ---------------- k_B: att-activation + q + scores/exp/den + proj(t-1) ----------------
__global__ __launch_bounds__(512) void k_B(Ptrs P, int t, int nAtt){
  __shared__ float sm[16640];
  int bid = blockIdx.x, tid = threadIdx.x;
  if (bid < nAtt){
    int b = bid>>1, h = bid&1;
    if (tid < 256) P.ctxN[b*512 + h*256 + tid] = 0.f;   // zero NEXT ctx buffer (no race w/ proj)
    // att LSTM activation (duplicated across the 2 h-halves; identical values -> benign)
    #pragma unroll
    for (int i=0;i<2;i++){
      int jj = tid + i*512;
      float gi=0.f, gf=0.f, gg=0.f, go=0.f;
      #pragma unroll
      for (int c=0;c<4;c++){
        const float* g = P.gpA + (size_t)(c*32+b)*4096;
        gi += g[jj]; gf += g[1024+jj]; gg += g[2048+jj]; go += g[3072+jj];
      }
      gi += P.bihA[jj]      + P.bhhA[jj];
      gf += P.bihA[1024+jj] + P.bhhA[1024+jj];
      gg += P.bihA[2048+jj] + P.bhhA[2048+jj];
      go += P.bihA[3072+jj] + P.bhhA[3072+jj];
      float c2 = sigf(gf)*P.acp[b*1024+jj] + sigf(gi)*tanhfast(gg);
      float hh = sigf(go)*tanhfast(c2);
      P.acn[b*1024+jj] = c2;
      P.ahn[b*1024+jj] = hh;
      sm[jj] = hh;
    }
    __syncthreads();
    // q = ah @ Wq^T  (128 outs)
    {
      int a = tid&127, kq = tid>>7;
      float p = 0.f;
      for (int k2=0; k2<256; k2+=4){
        int k = kq*256 + k2;
        float4 av = *(float4*)(sm + k);
        p += av.x*P.WqT[(k+0)*128+a] + av.y*P.WqT[(k+1)*128+a]
           + av.z*P.WqT[(k+2)*128+a] + av.w*P.WqT[(k+3)*128+a];
      }
      sm[1024 + kq*128 + a] = p;
    }
    __syncthreads();
    if (tid < 128) sm[1536+tid] = sm[1024+tid] + sm[1152+tid] + sm[1280+tid] + sm[1408+tid];
    __syncthreads();
    // scores for this half's 256 t positions
    int tl = tid>>1, ha = tid&1, s = h*256 + tl;
    const float* base = P.loc + ((size_t)b*512 + s)*128 + ha*64;  // loc includes pm
    const float* wsp = P.Wsc + ha*64;
    const float* qb  = sm + 1536 + ha*64;
    float p = 0.f;
    #pragma unroll
    for (int i=0;i<64;i+=4){
      float4 lv = *(const float4*)(base+i);
      float4 wv = *(const float4*)(wsp+i);
      float4 qv = *(const float4*)(qb+i);
      p += wv.x*tanhfast(qv.x+lv.x) + wv.y*tanhfast(qv.y+lv.y)
         + wv.z*tanhfast(qv.z+lv.z) + wv.w*tanhfast(qv.w+lv.w);
    }
    p += __shfl_xor(p, 1, 64);
    float ex = 0.f;
    if (ha == 0){
      float sc = p + P.bsc[0];        // tanh-bounded: exp safe without max-sub
      ex = __expf(sc);
      P.esc[b*512 + s] = ex;
    }
    #pragma unroll
    for (int d=1; d<64; d<<=1) ex += __shfl_xor(ex, d, 64);
    if ((tid&63)==0) atomicAdd(&P.den[b], ex);
  } else {
    // projection for step t-1: x = [dh(1024) | ctxP(512)]
    int eb = bid - nAtt;
    int wv_ = tid>>6, lane = tid&63;
    int b0 = (eb&1)*16;
    int row = (eb>>1)*8 + wv_;
    bool act = (row <= 80);
    const float* wrow = (row<80) ? (P.Wproj + (size_t)row*1536) : P.Wgate;
    float acc[16];
    #pragma unroll
    for (int bi=0;bi<16;bi++) acc[bi]=0.f;
    for (int i4=tid; i4<4096; i4+=512){
      int bi=i4>>8, kk=(i4&255)<<2;
      *(float4*)(sm + bi*1024 + kk) = *(const float4*)(P.dh + (b0+bi)*1024 + kk);
    }
    __syncthreads();
    if (act){
      #pragma unroll
      for (int kq=0;kq<4;kq++){
        int k0=kq*256+lane*4;
        float4 w4 = *(const float4*)(wrow + k0);
        #pragma unroll
        for (int bi=0;bi<16;bi++){
          float4 x = *(float4*)(sm + bi*1024 + k0);
          acc[bi] += x.x*w4.x + x.y*w4.y + x.z*w4.z + x.w*w4.w;
        }
      }
    }
    __syncthreads();
    for (int i4=tid; i4<2048; i4+=512){
      int bi=i4>>7, kk=(i4&127)<<2;
      *(float4*)(sm + bi*512 + kk) = *(const float4*)(P.ctxP + (b0+bi)*512 + kk);
    }
    __syncthreads();
    if (act){
      #pragma unroll
      for (int kq=0;kq<2;kq++){
        int k0=kq*256+lane*4;
        float4 w4 = *(const float4*)(wrow + 1024 + k0);
        #pragma unroll
        for (int bi=0;bi<16;bi++){
          float4 x = *(float4*)(sm + bi*512 + k0);
          acc[bi] += x.x*w4.x + x.y*w4.y + x.z*w4.z + x.w*w4.w;
        }
      }
      #pragma unroll
      for (int bi=0;bi<16;bi++){
        float v = acc[bi];
        #pragma unroll
        for (int d=1; d<64; d<<=1) v += __shfl_xor(v, d, 64);
        acc[bi]=v;
      }
      if (lane==0){
        float bias = (row<80)? P.bproj[row] : P.bgate[0];
        #pragma unroll
        for (int bi=0;bi<16;bi++){
          float v = acc[bi]+bias;
          if (row<80) P.out[(size_t)(b0+bi)*32000 + row*400 + (t-1)] = v;
          else        P.out[GATE_OFF + (b0+bi)*400 + (t-1)] = v;
        }
      }
    }
  }
}

// ---------------- k_C: normalize w, alignments out, awcum, ctxN = w·memory ----------------
__global__ __launch_bounds__(512) void k_C(Ptrs P, int t){
  __shared__ __align__(16) float wL[128];
  int bid = blockIdx.x, tid = threadIdx.x;
  int b = bid>>2, sb = bid&3, s0 = sb*128;
  if (tid < 128){
    int s = s0 + tid;
    float w = P.esc[b*512+s] / P.den[b];
    P.aw[b*512+s] = w;
    P.awc[b*512+s] += w;
    P.out[ALIGN_OFF + (size_t)b*204800 + (size_t)t*512 + s] = w;
    wL[tid] = w;
  }
  __syncthreads();
  int e = tid;
  float acc = 0.f;
  for (int i=0;i<128;i+=4){
    float4 wv = *(float4*)(wL + i);
    const float* mrow = P.mem + ((size_t)b*512 + s0+i)*512 + e;
    acc += wv.x*mrow[0] + wv.y*mrow[512] + wv.z*mrow[1024] + wv.w*mrow[1536];
  }
  atomicAdd(&P.ctxN[b*512 + e], acc);
}

// ---------------- k_D: dec-GEMM partials: x = [ah_t | ctx_t | dh_{t-1}], K=2560 ----------------
__global__ __launch_bounds__(512) void k_D(Ptrs P){
  __shared__ float sm[16640];
  int bid = blockIdx.x, tid = threadIdx.x;
  int w = tid>>6, lane = tid&63;
  int jt = bid>>2, c = bid&3;
  int j = jt*64 + lane;
  int kbase = c*640 + w*80;
  float acc[32];
  #pragma unroll
  for (int b=0;b<32;b++) acc[b]=0.f;
  for (int kt=0; kt<10; kt++){
    int k0 = kbase + kt*8;
    float wv[8];
    #pragma unroll
    for (int u=0;u<8;u++) wv[u] = P.WDT[(size_t)(k0+u)*4096 + j];
    const float* xb; int ld;
    if (k0 < 1024){      xb = P.ahn + k0;         ld = 1024; }
    else if (k0 < 1536){ xb = P.ctxN + (k0-1024); ld = 512; }
    else{                xb = P.dh  + (k0-1536);  ld = 1024; }
    #pragma unroll
    for (int b=0;b<32;b++){
      #pragma unroll
      for (int u=0;u<8;u++) acc[b] += wv[u]*xb[u];
      xb += ld;
    }
  }
  #pragma unroll
  for (int b=0;b<32;b++) sm[(w*32+b)*65 + lane] = acc[b];
  __syncthreads();
  #pragma unroll
  for (int i=0;i<4;i++){
    int o = tid + i*512;
    int j2 = o&63, b = o>>6;
    float s = 0.f;
    #pragma unroll
    for (int w2=0;w2<8;w2++) s += sm[(w2*32+b)*65 + j2];
    P.gpD[(size_t)(c*32+b)*4096 + jt*64 + j2] = s;
  }
}

// ---------------- host ----------------
extern "C" void kernel_launch(void* const* d_in, const int* in_sizes, int n_in,
                              void* d_out, int out_size, void* d_ws, size_t ws_size,
                              hipStream_t stream) {
  Ptrs P;
  P.mem   = (const float*)d_in[0];  P.dec   = (const float*)d_in[1];
  P.Wpre1 = (const float*)d_in[2];  P.Wpre2 = (const float*)d_in[3];
  P.WihA  = (const float*)d_in[4];  P.WhhA  = (const float*)d_in[5];
  P.bihA  = (const float*)d_in[6];  P.bhhA  = (const float*)d_in[7];
  P.WihD  = (const float*)d_in[8];  P.WhhD  = (const float*)d_in[9];
  P.bihD  = (const float*)d_in[10]; P.bhhD  = (const float*)d_in[11];
  P.Wq    = (const float*)d_in[12]; P.Wm    = (const float*)d_in[13];
  P.Wsc   = (const float*)d_in[14]; P.bsc   = (const float*)d_in[15];
  P.Wlc   = (const float*)d_in[16]; P.Wld   = (const float*)d_in[17];
  P.Wproj = (const float*)d_in[18]; P.bproj = (const float*)d_in[19];
  P.Wgate = (const float*)d_in[20]; P.bgate = (const float*)d_in[21];
  P.out = (float*)d_out;

  float* ws = (float*)d_ws;
  size_t o = 0;
  P.pm  = ws + o; o += 2097152;      // [32][512][128]
  P.pre = ws + o; o += 3276800;      // [400][32][256]
  P.loc = ws + o; o += 2097152;      // [32][512][128] (loc + pm)
  P.WqT = ws + o; o += 131072;
  P.Mc  = ws + o; o += 8192;
  P.W1T = ws + o; o += 20480;
  P.W2T = ws + o; o += 65536;
  P.WmT = ws + o; o += 65536;
  P.gpA = ws + o; o += 524288;       // [4][32][4096]
  P.gpD = ws + o; o += 524288;
  float* stateBase = ws + o;
  float* AH[2]; AH[0] = ws + o; o += 32768; AH[1] = ws + o; o += 32768;
  float* AC[2]; AC[0] = ws + o; o += 32768; AC[1] = ws + o; o += 32768;
  P.dh  = ws + o; o += 32768;
  P.dc  = ws + o; o += 32768;
  float* CT[2]; CT[0] = ws + o; o += 16384; CT[1] = ws + o; o += 16384;
  P.aw  = ws + o; o += 16384;
  P.awc = ws + o; o += 16384;
  P.den = ws + o; o += 64;
  int stateN = (int)((ws + o) - stateBase);
  P.esc = ws + o; o += 16384;
  P.WAT = ws + o; o += 7340032;      // [1792][4096]
  P.WDT = ws + o; o += 10485760;     // [2560][4096]
  P.p1  = P.WAT;                     // prologue scratch aliases WAT (overwritten by k_tA)

  P.ahp = AH[0]; P.ahn = AH[1]; P.acp = AC[0]; P.acn = AC[1];
  P.ctxP = CT[0]; P.ctxN = CT[1];

  hipLaunchKernelGGL(k_init, dim3((stateN+255)/256), dim3(256), 0, stream, stateBase, stateN);
  hipLaunchKernelGGL(k_xform, dim3(1135), dim3(256), 0, stream, P);
  hipLaunchKernelGGL(k_pn1, dim3(1600), dim3(256), 0, stream, P);
  hipLaunchKernelGGL(k_pn2, dim3(1600), dim3(256), 0, stream, P);
  hipLaunchKernelGGL(k_pm,  dim3(2048), dim3(256), 0, stream, P);
  hipLaunchKernelGGL(k_tA,  dim3(128*56), dim3(256), 0, stream, P);
  hipLaunchKernelGGL(k_tD,  dim3(128*80), dim3(256), 0, stream, P);

  for (int t=0; t<400; t++){
    Ptrs Q = P;
    Q.ahp = AH[t&1];     Q.ahn = AH[(t+1)&1];
    Q.acp = AC[t&1];     Q.acn = AC[(t+1)&1];
    Q.ctxP = CT[t&1];    Q.ctxN = CT[(t+1)&1];
    int nActD = t ? 32 : 0;
    int nProj = t ? 22 : 0;
    hipLaunchKernelGGL(k_A, dim3(256+256+nActD), dim3(512), 0, stream, Q, t, 256, 256, nActD);
    hipLaunchKernelGGL(k_B, dim3(64+nProj), dim3(512), 0, stream, Q, t, 64);
    hipLaunchKernelGGL(k_C, dim3(128), dim3(512), 0, stream, Q, t);
    hipLaunchKernelGGL(k_D, dim3(256), dim3(512), 0, stream, Q);
  }
  // tail: dec activation for t=399, then projection for t=399
  Ptrs Q = P;
  Q.ahp = AH[0]; Q.ahn = AH[1]; Q.acp = AC[0]; Q.acn = AC[1];
  Q.ctxP = CT[0]; Q.ctxN = CT[1];   // ctx_399 lives in CT[(399+1)&1] = CT[0]
  hipLaunchKernelGGL(k_A, dim3(32), dim3(512), 0, stream, Q, 400, 0, 0, 32);
  hipLaunchKernelGGL(k_B, dim3(22), dim3(512), 0, stream, Q, 400, 0);
}

// Round 5
// 33074.939 us; speedup vs baseline: 3.9510x; 1.4412x over previous
//
#include <hip/hip_runtime.h>

// B=32, T=512, E=512, TDEC=400, NMEL=80, RNN=1024, PRE=256, ADIM=128, KS=31
// outputs: mel [32][80][400] | gate [32][400] | align [32][400][512]
#define GATE_OFF  1024000
#define ALIGN_OFF 1036800

struct Ptrs {
  const float *mem, *dec, *Wpre1, *Wpre2, *WihA, *WhhA, *bihA, *bhhA,
              *WihD, *WhhD, *bihD, *bhhD, *Wq, *Wm, *Wsc, *bsc,
              *Wlc, *Wld, *Wproj, *bproj, *Wgate, *bgate;
  float *out;
  float *pm, *pre, *loc, *WqT, *Mc, *W1T, *W2T, *WmT, *p1, *WAT, *WDT, *gpA, *gpD;
  float *ahp, *ahn, *acp, *acn, *dh, *dc, *ctxP, *ctxN, *aw, *awc;
};

__device__ __forceinline__ float rcpf(float x){ return __builtin_amdgcn_rcpf(x); }
__device__ __forceinline__ float sigf(float x){
  x = fminf(fmaxf(x,-30.f),30.f);
  return rcpf(1.f+__expf(-x));
}
__device__ __forceinline__ float tanhfast(float x){
  x = fminf(fmaxf(x,-15.f),15.f);
  float e = __expf(2.f*x);
  return (e-1.f)*rcpf(e+1.f);
}

__global__ void k_init(float* p, int n){
  int i = blockIdx.x*256 + threadIdx.x;
  if (i < n) p[i] = 0.f;
}

__global__ void k_xform(Ptrs P){
  int i = blockIdx.x*256 + threadIdx.x;
  if (i < 20480){ int k=i>>8, p=i&255; P.W1T[i] = P.Wpre1[p*80 + k]; return; }
  i -= 20480;
  if (i < 65536){ int k=i>>8, p=i&255; P.W2T[i] = P.Wpre2[p*256 + k]; return; }
  i -= 65536;
  if (i < 131072){ int k=i>>7, a=i&127; P.WqT[i] = P.Wq[a*1024 + k]; return; }
  i -= 131072;
  if (i < 65536){ int e=i>>7, a=i&127; P.WmT[i] = P.Wm[a*512 + e]; return; }
  i -= 65536;
  if (i < 7936){
    int c = i/3968, r = i%3968, k = r>>7, a = r&127;
    float s = 0.f;
    for (int f=0; f<31; f++) s += P.Wld[a*31+f]*P.Wlc[f*62 + c*31 + k];
    P.Mc[i] = s;
  }
}

// big weight transposes: WAT[k][4096], WDT[k][4096]
__global__ __launch_bounds__(256) void k_tA(Ptrs P){
  __shared__ float tb[32][33];
  int bid = blockIdx.x, tid = threadIdx.x;
  int jt = bid/56, kt = bid%56;
  int j0 = jt*32, k0 = kt*32;
  int r = tid>>3, s = tid&7;
  const float* src; int ld, kk0;
  if (k0 < 768){ src = P.WihA; ld = 768;  kk0 = k0; }
  else         { src = P.WhhA; ld = 1024; kk0 = k0-768; }
  float4 v = *(const float4*)(src + (size_t)(j0+r)*ld + kk0 + s*4);
  tb[r][s*4+0]=v.x; tb[r][s*4+1]=v.y; tb[r][s*4+2]=v.z; tb[r][s*4+3]=v.w;
  __syncthreads();
  float4 o2; o2.x=tb[s*4+0][r]; o2.y=tb[s*4+1][r]; o2.z=tb[s*4+2][r]; o2.w=tb[s*4+3][r];
  *(float4*)(P.WAT + (size_t)(k0+r)*4096 + j0 + s*4) = o2;
}
__global__ __launch_bounds__(256) void k_tD(Ptrs P){
  __shared__ float tb[32][33];
  int bid = blockIdx.x, tid = threadIdx.x;
  int jt = bid/80, kt = bid%80;
  int j0 = jt*32, k0 = kt*32;
  int r = tid>>3, s = tid&7;
  const float* src; int ld, kk0;
  if (k0 < 1536){ src = P.WihD; ld = 1536; kk0 = k0; }
  else          { src = P.WhhD; ld = 1024; kk0 = k0-1536; }
  float4 v = *(const float4*)(src + (size_t)(j0+r)*ld + kk0 + s*4);
  tb[r][s*4+0]=v.x; tb[r][s*4+1]=v.y; tb[r][s*4+2]=v.z; tb[r][s*4+3]=v.w;
  __syncthreads();
  float4 o2; o2.x=tb[s*4+0][r]; o2.y=tb[s*4+1][r]; o2.z=tb[s*4+2][r]; o2.w=tb[s*4+3][r];
  *(float4*)(P.WDT + (size_t)(k0+r)*4096 + j0 + s*4) = o2;
}

__global__ __launch_bounds__(256) void k_pn1(Ptrs P){
  __shared__ __align__(16) float pinL[8*80];
  int bid = blockIdx.x, tid = threadIdx.x;
  int r0 = bid*8;
  for (int i=tid; i<640; i+=256){
    int bi = i/80, m = i%80;
    int row = r0+bi, tt = row>>5, b = row&31;
    pinL[bi*80+m] = (tt==0) ? 0.f : P.dec[(size_t)b*32000 + m*400 + (tt-1)];
  }
  __syncthreads();
  int p = tid;
  float acc[8];
  #pragma unroll
  for (int bi=0;bi<8;bi++) acc[bi]=0.f;
  #pragma unroll
  for (int kq=0; kq<20; kq++){
    int k0 = kq*4;
    float w0 = P.W1T[(k0+0)*256+p], w1 = P.W1T[(k0+1)*256+p];
    float w2 = P.W1T[(k0+2)*256+p], w3 = P.W1T[(k0+3)*256+p];
    #pragma unroll
    for (int bi=0;bi<8;bi++){
      float4 x = *(float4*)(pinL + bi*80 + k0);
      acc[bi] += x.x*w0 + x.y*w1 + x.z*w2 + x.w*w3;
    }
  }
  #pragma unroll
  for (int bi=0;bi<8;bi++) P.p1[(size_t)(r0+bi)*256 + p] = fmaxf(acc[bi],0.f);
}

__global__ __launch_bounds__(256) void k_pn2(Ptrs P){
  __shared__ __align__(16) float xL[8*256];
  int bid = blockIdx.x, tid = threadIdx.x;
  size_t r0 = (size_t)bid*8;
  for (int i4=tid; i4<512; i4+=256)
    *(float4*)(xL + i4*4) = *(const float4*)(P.p1 + r0*256 + i4*4);
  __syncthreads();
  int p = tid;
  float acc[8];
  #pragma unroll
  for (int bi=0;bi<8;bi++) acc[bi]=0.f;
  for (int kq=0; kq<64; kq++){
    int k0 = kq*4;
    float w0 = P.W2T[(k0+0)*256+p], w1 = P.W2T[(k0+1)*256+p];
    float w2 = P.W2T[(k0+2)*256+p], w3 = P.W2T[(k0+3)*256+p];
    #pragma unroll
    for (int bi=0;bi<8;bi++){
      float4 x = *(float4*)(xL + bi*256 + k0);
      acc[bi] += x.x*w0 + x.y*w1 + x.z*w2 + x.w*w3;
    }
  }
  #pragma unroll
  for (int bi=0;bi<8;bi++) P.pre[(r0+bi)*256 + p] = fmaxf(acc[bi],0.f);
}

__global__ __launch_bounds__(256) void k_pm(Ptrs P){
  __shared__ __align__(16) float memL[8*512];
  int bid = blockIdx.x, tid = threadIdx.x;
  size_t r0 = (size_t)bid*8;
  for (int i4=tid; i4<1024; i4+=256)
    *(float4*)(memL + i4*4) = *(const float4*)(P.mem + r0*512 + i4*4);
  __syncthreads();
  int a = tid&127, rq = tid>>7;
  float acc[4];
  #pragma unroll
  for (int ri=0;ri<4;ri++) acc[ri]=0.f;
  for (int kq=0; kq<128; kq++){
    int k0 = kq*4;
    float w0 = P.WmT[(k0+0)*128+a], w1 = P.WmT[(k0+1)*128+a];
    float w2 = P.WmT[(k0+2)*128+a], w3 = P.WmT[(k0+3)*128+a];
    #pragma unroll
    for (int ri=0;ri<4;ri++){
      float4 x = *(float4*)(memL + (rq*4+ri)*512 + k0);
      acc[ri] += x.x*w0 + x.y*w1 + x.z*w2 + x.w*w3;
    }
  }
  #pragma unroll
  for (int ri=0;ri<4;ri++) P.pm[(r0 + rq*4+ri)*128 + a] = acc[ri];
}

// ---------------- k_A: att-GEMM (LDS-staged, jr=2) + conv + dec-act(t-1) ----------------
__global__ __launch_bounds__(512, 4) void k_A(Ptrs P, int t, int nG, int nConv, int nActD){
  __shared__ float sm[16448];   // xs (7168) | reduce (16384)
  int bid = blockIdx.x, tid = threadIdx.x;
  int wid = tid>>6, lane = tid&63;

  if (bid < nG){
    // GEMM: block = 128 j (jt) x 224 k (c); x = [pre_t | ctxP | ahp], K=1792
    int jt = bid>>3, c = bid&7;
    // stage x chunk: xs[32][224]
    for (int i4 = tid; i4 < 1792; i4 += 512){
      int bi = i4/56, kq = i4%56;
      int k = c*224 + kq*4;
      float4 v;
      if (k < 256)      v = *(const float4*)(P.pre + (size_t)(t*32+bi)*256 + k);
      else if (k < 768) v = *(const float4*)(P.ctxP + bi*512 + (k-256));
      else              v = *(const float4*)(P.ahp + bi*1024 + (k-768));
      *(float4*)(sm + bi*224 + kq*4) = v;
    }
    __syncthreads();
    int j0 = jt*128 + lane;
    float acc0[32], acc1[32];
    #pragma unroll
    for (int b=0;b<32;b++){ acc0[b]=0.f; acc1[b]=0.f; }
    int klb = wid*28;
    for (int kt4=0; kt4<7; kt4++){
      int kl = klb + kt4*4;
      size_t kg = (size_t)(c*224 + kl);
      float w00 = P.WAT[(kg+0)*4096+j0], w01 = P.WAT[(kg+1)*4096+j0],
            w02 = P.WAT[(kg+2)*4096+j0], w03 = P.WAT[(kg+3)*4096+j0];
      float w10 = P.WAT[(kg+0)*4096+j0+64], w11 = P.WAT[(kg+1)*4096+j0+64],
            w12 = P.WAT[(kg+2)*4096+j0+64], w13 = P.WAT[(kg+3)*4096+j0+64];
      #pragma unroll
      for (int bq=0; bq<4; bq++){
        float4 xv[8];
        #pragma unroll
        for (int u=0;u<8;u++) xv[u] = *(float4*)(sm + (bq*8+u)*224 + kl);
        #pragma unroll
        for (int u=0;u<8;u++){
          int b = bq*8+u;
          acc0[b] += xv[u].x*w00 + xv[u].y*w01 + xv[u].z*w02 + xv[u].w*w03;
          acc1[b] += xv[u].x*w10 + xv[u].y*w11 + xv[u].z*w12 + xv[u].w*w13;
        }
      }
    }
    // two-round cross-wave reduce
    __syncthreads();
    #pragma unroll
    for (int b=0;b<32;b++) sm[(wid*32+b)*64 + lane] = acc0[b];
    __syncthreads();
    #pragma unroll
    for (int i=0;i<4;i++){
      int o = tid + i*512; int j2 = o&63, b = o>>6;
      float s = 0.f;
      #pragma unroll
      for (int w2=0;w2<8;w2++) s += sm[(w2*32+b)*64 + j2];
      P.gpA[(size_t)(c*32+b)*4096 + jt*128 + j2] = s;
    }
    __syncthreads();
    #pragma unroll
    for (int b=0;b<32;b++) sm[(wid*32+b)*64 + lane] = acc1[b];
    __syncthreads();
    #pragma unroll
    for (int i=0;i<4;i++){
      int o = tid + i*512; int j2 = o&63, b = o>>6;
      float s = 0.f;
      #pragma unroll
      for (int w2=0;w2<8;w2++) s += sm[(w2*32+b)*64 + j2];
      P.gpA[(size_t)(c*32+b)*4096 + jt*128 + 64 + j2] = s;
    }
  } else if (bid < nG+nConv){
    // location conv (+pm pre-add), 2 channel passes to limit VGPR
    int gw = (bid-nG)*8 + wid;
    int b = gw>>6, rr = gw&63, t0 = (rr>>1)*16, a = (rr&1)*64 + lane;
    float acc[16];
    #pragma unroll
    for (int tl=0;tl<16;tl++) acc[tl]=0.f;
    #pragma unroll
    for (int c=0;c<2;c++){
      const float* src = c ? P.awc : P.aw;
      float awin[46];
      #pragma unroll
      for (int i=0;i<46;i++){
        int tt = t0-15+i;
        awin[i] = (tt>=0 && tt<512) ? src[b*512+tt] : 0.f;
      }
      #pragma unroll
      for (int k=0;k<31;k++){
        float mcv = P.Mc[(c*31+k)*128 + a];
        #pragma unroll
        for (int tl=0;tl<16;tl++) acc[tl] += awin[tl + k]*mcv;
      }
    }
    #pragma unroll
    for (int tl=0;tl<16;tl++){
      size_t idx = ((size_t)b*512 + t0+tl)*128 + a;
      P.loc[idx] = acc[tl] + P.pm[idx];
    }
  } else {
    // dec activation for step t-1 (8 partials)
    int b = bid - nG - nConv;
    #pragma unroll
    for (int i=0;i<2;i++){
      int jj = tid + i*512;
      float gi=0.f, gf=0.f, gg=0.f, go=0.f;
      #pragma unroll
      for (int c=0;c<8;c++){
        const float* g = P.gpD + (size_t)(c*32+b)*4096;
        gi += g[jj]; gf += g[1024+jj]; gg += g[2048+jj]; go += g[3072+jj];
      }
      gi += P.bihD[jj]      + P.bhhD[jj];
      gf += P.bihD[1024+jj] + P.bhhD[1024+jj];
      gg += P.bihD[2048+jj] + P.bhhD[2048+jj];
      go += P.bihD[3072+jj] + P.bhhD[3072+jj];
      float c2 = sigf(gf)*P.dc[b*1024+jj] + sigf(gi)*tanhfast(gg);
      float hh = sigf(go)*tanhfast(c2);
      P.dc[b*1024+jj] = c2;
      P.dh[b*1024+jj] = hh;
    }
  }
}

// ---------------- k_BC: att-act + q + scores + softmax + ctx (1 block/b) + proj(t-1) ----------------
__global__ __launch_bounds__(512) void k_BC(Ptrs P, int t, int nAtt){
  __shared__ float sm[16448];
  // att layout: hh[0,1024) qp[1024,1536) qL[1536,1664) w[1664,2176) red[2176,2184)
  int bid = blockIdx.x, tid = threadIdx.x;
  int wid = tid>>6, lane = tid&63;
  if (bid < nAtt){
    int b = bid;
    // att LSTM activation (8 partials)
    #pragma unroll
    for (int i=0;i<2;i++){
      int jj = tid + i*512;
      float gi=0.f, gf=0.f, gg=0.f, go=0.f;
      #pragma unroll
      for (int c=0;c<8;c++){
        const float* g = P.gpA + (size_t)(c*32+b)*4096;
        gi += g[jj]; gf += g[1024+jj]; gg += g[2048+jj]; go += g[3072+jj];
      }
      gi += P.bihA[jj]      + P.bhhA[jj];
      gf += P.bihA[1024+jj] + P.bhhA[1024+jj];
      gg += P.bihA[2048+jj] + P.bhhA[2048+jj];
      go += P.bihA[3072+jj] + P.bhhA[3072+jj];
      float c2 = sigf(gf)*P.acp[b*1024+jj] + sigf(gi)*tanhfast(gg);
      float hh = sigf(go)*tanhfast(c2);
      P.acn[b*1024+jj] = c2;
      P.ahn[b*1024+jj] = hh;
      sm[jj] = hh;
    }
    __syncthreads();
    // q = ah @ Wq^T
    {
      int a = tid&127, kq = tid>>7;
      float p = 0.f;
      for (int k2=0; k2<256; k2+=4){
        int k = kq*256 + k2;
        float4 av = *(float4*)(sm + k);
        p += av.x*P.WqT[(k+0)*128+a] + av.y*P.WqT[(k+1)*128+a]
           + av.z*P.WqT[(k+2)*128+a] + av.w*P.WqT[(k+3)*128+a];
      }
      sm[1024 + kq*128 + a] = p;
    }
    __syncthreads();
    if (tid < 128) sm[1536+tid] = sm[1024+tid] + sm[1152+tid] + sm[1280+tid] + sm[1408+tid];
    __syncthreads();
    // scores: thread = t-position
    int s = tid;
    const float* lrow = P.loc + ((size_t)b*512 + s)*128;
    float sc = 0.f;
    #pragma unroll
    for (int a=0; a<128; a+=4){
      float4 lv = *(const float4*)(lrow + a);
      float4 wv = *(const float4*)(P.Wsc + a);
      sc += wv.x*tanhfast(sm[1536+a+0]+lv.x) + wv.y*tanhfast(sm[1536+a+1]+lv.y)
          + wv.z*tanhfast(sm[1536+a+2]+lv.z) + wv.w*tanhfast(sm[1536+a+3]+lv.w);
    }
    float ex = __expf(sc + P.bsc[0]);   // tanh-bounded: safe without max-sub
    float exs = ex;
    #pragma unroll
    for (int d=1; d<64; d<<=1) exs += __shfl_xor(exs, d, 64);
    if (lane==0) sm[2176+wid] = exs;
    __syncthreads();
    float den = sm[2176]+sm[2177]+sm[2178]+sm[2179]+sm[2180]+sm[2181]+sm[2182]+sm[2183];
    float w = ex / den;
    P.aw[b*512+s] = w;
    P.awc[b*512+s] += w;
    P.out[ALIGN_OFF + (size_t)b*204800 + (size_t)t*512 + s] = w;
    sm[1664+s] = w;
    __syncthreads();
    // ctx = w · memory (thread = e)
    int e = tid;
    float acc = 0.f;
    for (int t2=0; t2<512; t2+=4){
      float4 wv = *(float4*)(sm + 1664 + t2);
      const float* mr = P.mem + ((size_t)b*512 + t2)*512 + e;
      acc += wv.x*mr[0] + wv.y*mr[512] + wv.z*mr[1024] + wv.w*mr[1536];
    }
    P.ctxN[b*512+e] = acc;
  } else {
    // projection for step t-1: x = [dh(1024) | ctxP(512)]
    int eb = bid - nAtt;
    int b0 = (eb&1)*16;
    int row = (eb>>1)*8 + wid;
    bool act = (row <= 80);
    const float* wrow = (row<80) ? (P.Wproj + (size_t)row*1536) : P.Wgate;
    float acc[16];
    #pragma unroll
    for (int bi=0;bi<16;bi++) acc[bi]=0.f;
    for (int i4=tid; i4<4096; i4+=512){
      int bi=i4>>8, kk=(i4&255)<<2;
      *(float4*)(sm + bi*1024 + kk) = *(const float4*)(P.dh + (b0+bi)*1024 + kk);
    }
    __syncthreads();
    if (act){
      #pragma unroll
      for (int kq=0;kq<4;kq++){
        int k0=kq*256+lane*4;
        float4 w4 = *(const float4*)(wrow + k0);
        #pragma unroll
        for (int bi=0;bi<16;bi++){
          float4 x = *(float4*)(sm + bi*1024 + k0);
          acc[bi] += x.x*w4.x + x.y*w4.y + x.z*w4.z + x.w*w4.w;
        }
      }
    }
    __syncthreads();
    for (int i4=tid; i4<2048; i4+=512){
      int bi=i4>>7, kk=(i4&127)<<2;
      *(float4*)(sm + bi*512 + kk) = *(const float4*)(P.ctxP + (b0+bi)*512 + kk);
    }
    __syncthreads();
    if (act){
      #pragma unroll
      for (int kq=0;kq<2;kq++){
        int k0=kq*256+lane*4;
        float4 w4 = *(const float4*)(wrow + 1024 + k0);
        #pragma unroll
        for (int bi=0;bi<16;bi++){
          float4 x = *(float4*)(sm + bi*512 + k0);
          acc[bi] += x.x*w4.x + x.y*w4.y + x.z*w4.z + x.w*w4.w;
        }
      }
      #pragma unroll
      for (int bi=0;bi<16;bi++){
        float v = acc[bi];
        #pragma unroll
        for (int d=1; d<64; d<<=1) v += __shfl_xor(v, d, 64);
        acc[bi]=v;
      }
      if (lane==0){
        float bias = (row<80)? P.bproj[row] : P.bgate[0];
        #pragma unroll
        for (int bi=0;bi<16;bi++){
          float v = acc[bi]+bias;
          if (row<80) P.out[(size_t)(b0+bi)*32000 + row*400 + (t-1)] = v;
          else        P.out[GATE_OFF + (b0+bi)*400 + (t-1)] = v;
        }
      }
    }
  }
}

// ---------------- k_D: dec-GEMM (LDS-staged, jr=2): x = [ahn | ctxN | dh], K=2560 ----------------
__global__ __launch_bounds__(512, 4) void k_D(Ptrs P){
  __shared__ float sm[16448];   // xs (10240) | reduce (16384)
  int bid = blockIdx.x, tid = threadIdx.x;
  int wid = tid>>6, lane = tid&63;
  int jt = bid>>3, c = bid&7;
  for (int i4 = tid; i4 < 2560; i4 += 512){
    int bi = i4/80, kq = i4%80;
    int k = c*320 + kq*4;
    float4 v;
    if (k < 1024)      v = *(const float4*)(P.ahn + bi*1024 + k);
    else if (k < 1536) v = *(const float4*)(P.ctxN + bi*512 + (k-1024));
    else               v = *(const float4*)(P.dh + bi*1024 + (k-1536));
    *(float4*)(sm + bi*320 + kq*4) = v;
  }
  __syncthreads();
  int j0 = jt*128 + lane;
  float acc0[32], acc1[32];
  #pragma unroll
  for (int b=0;b<32;b++){ acc0[b]=0.f; acc1[b]=0.f; }
  int klb = wid*40;
  for (int kt4=0; kt4<10; kt4++){
    int kl = klb + kt4*4;
    size_t kg = (size_t)(c*320 + kl);
    float w00 = P.WDT[(kg+0)*4096+j0], w01 = P.WDT[(kg+1)*4096+j0],
          w02 = P.WDT[(kg+2)*4096+j0], w03 = P.WDT[(kg+3)*4096+j0];
    float w10 = P.WDT[(kg+0)*4096+j0+64], w11 = P.WDT[(kg+1)*4096+j0+64],
          w12 = P.WDT[(kg+2)*4096+j0+64], w13 = P.WDT[(kg+3)*4096+j0+64];
    #pragma unroll
    for (int bq=0; bq<4; bq++){
      float4 xv[8];
      #pragma unroll
      for (int u=0;u<8;u++) xv[u] = *(float4*)(sm + (bq*8+u)*320 + kl);
      #pragma unroll
      for (int u=0;u<8;u++){
        int b = bq*8+u;
        acc0[b] += xv[u].x*w00 + xv[u].y*w01 + xv[u].z*w02 + xv[u].w*w03;
        acc1[b] += xv[u].x*w10 + xv[u].y*w11 + xv[u].z*w12 + xv[u].w*w13;
      }
    }
  }
  __syncthreads();
  #pragma unroll
  for (int b=0;b<32;b++) sm[(wid*32+b)*64 + lane] = acc0[b];
  __syncthreads();
  #pragma unroll
  for (int i=0;i<4;i++){
    int o = tid + i*512; int j2 = o&63, b = o>>6;
    float s = 0.f;
    #pragma unroll
    for (int w2=0;w2<8;w2++) s += sm[(w2*32+b)*64 + j2];
    P.gpD[(size_t)(c*32+b)*4096 + jt*128 + j2] = s;
  }
  __syncthreads();
  #pragma unroll
  for (int b=0;b<32;b++) sm[(wid*32+b)*64 + lane] = acc1[b];
  __syncthreads();
  #pragma unroll
  for (int i=0;i<4;i++){
    int o = tid + i*512; int j2 = o&63, b = o>>6;
    float s = 0.f;
    #pragma unroll
    for (int w2=0;w2<8;w2++) s += sm[(w2*32+b)*64 + j2];
    P.gpD[(size_t)(c*32+b)*4096 + jt*128 + 64 + j2] = s;
  }
}

// ---------------- host ----------------
extern "C" void kernel_launch(void* const* d_in, const int* in_sizes, int n_in,
                              void* d_out, int out_size, void* d_ws, size_t ws_size,
                              hipStream_t stream) {
  Ptrs P;
  P.mem   = (const float*)d_in[0];  P.dec   = (const float*)d_in[1];
  P.Wpre1 = (const float*)d_in[2];  P.Wpre2 = (const float*)d_in[3];
  P.WihA  = (const float*)d_in[4];  P.WhhA  = (const float*)d_in[5];
  P.bihA  = (const float*)d_in[6];  P.bhhA  = (const float*)d_in[7];
  P.WihD  = (const float*)d_in[8];  P.WhhD  = (const float*)d_in[9];
  P.bihD  = (const float*)d_in[10]; P.bhhD  = (const float*)d_in[11];
  P.Wq    = (const float*)d_in[12]; P.Wm    = (const float*)d_in[13];
  P.Wsc   = (const float*)d_in[14]; P.bsc   = (const float*)d_in[15];
  P.Wlc   = (const float*)d_in[16]; P.Wld   = (const float*)d_in[17];
  P.Wproj = (const float*)d_in[18]; P.bproj = (const float*)d_in[19];
  P.Wgate = (const float*)d_in[20]; P.bgate = (const float*)d_in[21];
  P.out = (float*)d_out;

  float* ws = (float*)d_ws;
  size_t o = 0;
  P.pm  = ws + o; o += 2097152;
  P.pre = ws + o; o += 3276800;
  P.loc = ws + o; o += 2097152;
  P.WqT = ws + o; o += 131072;
  P.Mc  = ws + o; o += 8192;
  P.W1T = ws + o; o += 20480;
  P.W2T = ws + o; o += 65536;
  P.WmT = ws + o; o += 65536;
  P.gpA = ws + o; o += 1048576;      // [8][32][4096]
  P.gpD = ws + o; o += 1048576;
  float* stateBase = ws + o;
  float* AH[2]; AH[0] = ws + o; o += 32768; AH[1] = ws + o; o += 32768;
  float* AC[2]; AC[0] = ws + o; o += 32768; AC[1] = ws + o; o += 32768;
  P.dh  = ws + o; o += 32768;
  P.dc  = ws + o; o += 32768;
  float* CT[2]; CT[0] = ws + o; o += 16384; CT[1] = ws + o; o += 16384;
  P.aw  = ws + o; o += 16384;
  P.awc = ws + o; o += 16384;
  int stateN = (int)((ws + o) - stateBase);
  P.WAT = ws + o; o += 7340032;      // [1792][4096]
  P.WDT = ws + o; o += 10485760;     // [2560][4096]
  P.p1  = P.WAT;                     // prologue scratch aliases WAT

  P.ahp = AH[0]; P.ahn = AH[1]; P.acp = AC[0]; P.acn = AC[1];
  P.ctxP = CT[0]; P.ctxN = CT[1];

  hipLaunchKernelGGL(k_init, dim3((stateN+255)/256), dim3(256), 0, stream, stateBase, stateN);
  hipLaunchKernelGGL(k_xform, dim3(1135), dim3(256), 0, stream, P);
  hipLaunchKernelGGL(k_pn1, dim3(1600), dim3(256), 0, stream, P);
  hipLaunchKernelGGL(k_pn2, dim3(1600), dim3(256), 0, stream, P);
  hipLaunchKernelGGL(k_pm,  dim3(2048), dim3(256), 0, stream, P);
  hipLaunchKernelGGL(k_tA,  dim3(128*56), dim3(256), 0, stream, P);
  hipLaunchKernelGGL(k_tD,  dim3(128*80), dim3(256), 0, stream, P);

  for (int t=0; t<400; t++){
    Ptrs Q = P;
    Q.ahp = AH[t&1];     Q.ahn = AH[(t+1)&1];
    Q.acp = AC[t&1];     Q.acn = AC[(t+1)&1];
    Q.ctxP = CT[t&1];    Q.ctxN = CT[(t+1)&1];
    int nActD = t ? 32 : 0;
    int nProj = t ? 22 : 0;
    hipLaunchKernelGGL(k_A, dim3(512+nActD), dim3(512), 0, stream, Q, t, 256, 256, nActD);
    hipLaunchKernelGGL(k_BC, dim3(32+nProj), dim3(512), 0, stream, Q, t, 32);
    hipLaunchKernelGGL(k_D, dim3(256), dim3(512), 0, stream, Q);
  }
  // tail: dec activation for t=399, then projection for t=399
  Ptrs Q = P;
  Q.ahp = AH[0]; Q.ahn = AH[1]; Q.acp = AC[0]; Q.acn = AC[1];
  Q.ctxP = CT[0]; Q.ctxN = CT[1];   // ctx_399 lives in CT[0]
  hipLaunchKernelGGL(k_A, dim3(32), dim3(512), 0, stream, Q, 400, 0, 0, 32);
  hipLaunchKernelGGL(k_BC, dim3(22), dim3(512), 0, stream, Q, 400, 0);
}

// Round 6
// 31871.881 us; speedup vs baseline: 4.1001x; 1.0377x over previous
//
#include <hip/hip_runtime.h>
#include <hip/hip_fp16.h>

// B=32, T=512, E=512, TDEC=400, NMEL=80, RNN=1024, PRE=256, ADIM=128, KS=31
// outputs: mel [32][80][400] | gate [32][400] | align [32][400][512]
#define GATE_OFF  1024000
#define ALIGN_OFF 1036800

struct Ptrs {
  const float *mem, *dec, *Wpre1, *Wpre2, *WihA, *WhhA, *bihA, *bhhA,
              *WihD, *WhhD, *bihD, *bhhD, *Wq, *Wm, *Wsc, *bsc,
              *Wlc, *Wld, *Wproj, *bproj, *Wgate, *bgate;
  float *out;
  float *pre, *Mc, *W1T, *W2T, *WmT, *p1, *gpA, *gpD;
  __half *pmH, *locH, *WqTh, *WATh, *WDTh, *memH;
  float *ahp, *ahn, *acp, *acn, *dh, *dc, *ctxP, *ctxN, *aw, *awc;
};

__device__ __forceinline__ float rcpf(float x){ return __builtin_amdgcn_rcpf(x); }
__device__ __forceinline__ float sigf(float x){
  x = fminf(fmaxf(x,-30.f),30.f);
  return rcpf(1.f+__expf(-x));
}
__device__ __forceinline__ float tanhfast(float x){
  x = fminf(fmaxf(x,-15.f),15.f);
  float e = __expf(2.f*x);
  return (e-1.f)*rcpf(e+1.f);
}

__global__ void k_init(float* p, int n){
  int i = blockIdx.x*256 + threadIdx.x;
  if (i < n) p[i] = 0.f;
}

// mem -> fp16 copy (for ctx product)
__global__ __launch_bounds__(1024) void k_memh(Ptrs P){
  int i = blockIdx.x*1024 + threadIdx.x;
  if (i < 8388608) P.memH[i] = __float2half(P.mem[i]);
}

__global__ void k_xform(Ptrs P){
  int i = blockIdx.x*256 + threadIdx.x;
  if (i < 20480){ int k=i>>8, p=i&255; P.W1T[i] = P.Wpre1[p*80 + k]; return; }
  i -= 20480;
  if (i < 65536){ int k=i>>8, p=i&255; P.W2T[i] = P.Wpre2[p*256 + k]; return; }
  i -= 65536;
  if (i < 131072){ int k=i>>7, a=i&127; P.WqTh[i] = __float2half(P.Wq[a*1024 + k]); return; }
  i -= 131072;
  if (i < 65536){ int e=i>>7, a=i&127; P.WmT[i] = P.Wm[a*512 + e]; return; }
  i -= 65536;
  if (i < 7936){
    int c = i/3968, r = i%3968, k = r>>7, a = r&127;
    float s = 0.f;
    for (int f=0; f<31; f++) s += P.Wld[a*31+f]*P.Wlc[f*62 + c*31 + k];
    P.Mc[i] = s;
  }
}

// big weight transposes -> fp16: WATh[k][4096], WDTh[k][4096]
__global__ __launch_bounds__(256) void k_tA(Ptrs P){
  __shared__ float tb[32][33];
  int bid = blockIdx.x, tid = threadIdx.x;
  int jt = bid/56, kt = bid%56;
  int j0 = jt*32, k0 = kt*32;
  int r = tid>>3, s = tid&7;
  const float* src; int ld, kk0;
  if (k0 < 768){ src = P.WihA; ld = 768;  kk0 = k0; }
  else         { src = P.WhhA; ld = 1024; kk0 = k0-768; }
  float4 v = *(const float4*)(src + (size_t)(j0+r)*ld + kk0 + s*4);
  tb[r][s*4+0]=v.x; tb[r][s*4+1]=v.y; tb[r][s*4+2]=v.z; tb[r][s*4+3]=v.w;
  __syncthreads();
  size_t ob = (size_t)(k0+r)*4096 + j0 + s*4;
  P.WATh[ob+0] = __float2half(tb[s*4+0][r]);
  P.WATh[ob+1] = __float2half(tb[s*4+1][r]);
  P.WATh[ob+2] = __float2half(tb[s*4+2][r]);
  P.WATh[ob+3] = __float2half(tb[s*4+3][r]);
}
__global__ __launch_bounds__(256) void k_tD(Ptrs P){
  __shared__ float tb[32][33];
  int bid = blockIdx.x, tid = threadIdx.x;
  int jt = bid/80, kt = bid%80;
  int j0 = jt*32, k0 = kt*32;
  int r = tid>>3, s = tid&7;
  const float* src; int ld, kk0;
  if (k0 < 1536){ src = P.WihD; ld = 1536; kk0 = k0; }
  else          { src = P.WhhD; ld = 1024; kk0 = k0-1536; }
  float4 v = *(const float4*)(src + (size_t)(j0+r)*ld + kk0 + s*4);
  tb[r][s*4+0]=v.x; tb[r][s*4+1]=v.y; tb[r][s*4+2]=v.z; tb[r][s*4+3]=v.w;
  __syncthreads();
  size_t ob = (size_t)(k0+r)*4096 + j0 + s*4;
  P.WDTh[ob+0] = __float2half(tb[s*4+0][r]);
  P.WDTh[ob+1] = __float2half(tb[s*4+1][r]);
  P.WDTh[ob+2] = __float2half(tb[s*4+2][r]);
  P.WDTh[ob+3] = __float2half(tb[s*4+3][r]);
}

__global__ __launch_bounds__(256) void k_pn1(Ptrs P){
  __shared__ __align__(16) float pinL[8*80];
  int bid = blockIdx.x, tid = threadIdx.x;
  int r0 = bid*8;
  for (int i=tid; i<640; i+=256){
    int bi = i/80, m = i%80;
    int row = r0+bi, tt = row>>5, b = row&31;
    pinL[bi*80+m] = (tt==0) ? 0.f : P.dec[(size_t)b*32000 + m*400 + (tt-1)];
  }
  __syncthreads();
  int p = tid;
  float acc[8];
  #pragma unroll
  for (int bi=0;bi<8;bi++) acc[bi]=0.f;
  #pragma unroll
  for (int kq=0; kq<20; kq++){
    int k0 = kq*4;
    float w0 = P.W1T[(k0+0)*256+p], w1 = P.W1T[(k0+1)*256+p];
    float w2 = P.W1T[(k0+2)*256+p], w3 = P.W1T[(k0+3)*256+p];
    #pragma unroll
    for (int bi=0;bi<8;bi++){
      float4 x = *(float4*)(pinL + bi*80 + k0);
      acc[bi] += x.x*w0 + x.y*w1 + x.z*w2 + x.w*w3;
    }
  }
  #pragma unroll
  for (int bi=0;bi<8;bi++) P.p1[(size_t)(r0+bi)*256 + p] = fmaxf(acc[bi],0.f);
}

__global__ __launch_bounds__(256) void k_pn2(Ptrs P){
  __shared__ __align__(16) float xL[8*256];
  int bid = blockIdx.x, tid = threadIdx.x;
  size_t r0 = (size_t)bid*8;
  for (int i4=tid; i4<512; i4+=256)
    *(float4*)(xL + i4*4) = *(const float4*)(P.p1 + r0*256 + i4*4);
  __syncthreads();
  int p = tid;
  float acc[8];
  #pragma unroll
  for (int bi=0;bi<8;bi++) acc[bi]=0.f;
  for (int kq=0; kq<64; kq++){
    int k0 = kq*4;
    float w0 = P.W2T[(k0+0)*256+p], w1 = P.W2T[(k0+1)*256+p];
    float w2 = P.W2T[(k0+2)*256+p], w3 = P.W2T[(k0+3)*256+p];
    #pragma unroll
    for (int bi=0;bi<8;bi++){
      float4 x = *(float4*)(xL + bi*256 + k0);
      acc[bi] += x.x*w0 + x.y*w1 + x.z*w2 + x.w*w3;
    }
  }
  #pragma unroll
  for (int bi=0;bi<8;bi++) P.pre[(r0+bi)*256 + p] = fmaxf(acc[bi],0.f);
}

__global__ __launch_bounds__(256) void k_pm(Ptrs P){
  __shared__ __align__(16) float memL[8*512];
  int bid = blockIdx.x, tid = threadIdx.x;
  size_t r0 = (size_t)bid*8;
  for (int i4=tid; i4<1024; i4+=256)
    *(float4*)(memL + i4*4) = *(const float4*)(P.mem + r0*512 + i4*4);
  __syncthreads();
  int a = tid&127, rq = tid>>7;
  float acc[4];
  #pragma unroll
  for (int ri=0;ri<4;ri++) acc[ri]=0.f;
  for (int kq=0; kq<128; kq++){
    int k0 = kq*4;
    float w0 = P.WmT[(k0+0)*128+a], w1 = P.WmT[(k0+1)*128+a];
    float w2 = P.WmT[(k0+2)*128+a], w3 = P.WmT[(k0+3)*128+a];
    #pragma unroll
    for (int ri=0;ri<4;ri++){
      float4 x = *(float4*)(memL + (rq*4+ri)*512 + k0);
      acc[ri] += x.x*w0 + x.y*w1 + x.z*w2 + x.w*w3;
    }
  }
  #pragma unroll
  for (int ri=0;ri<4;ri++) P.pmH[(r0 + rq*4+ri)*128 + a] = __float2half(acc[ri]);
}

// ---------------- k_A: att-GEMM (LDS-staged, jr=2, fp16 W) + conv + dec-act(t-1) ----------------
__global__ __launch_bounds__(512, 4) void k_A(Ptrs P, int t, int nG, int nConv, int nActD){
  __shared__ float sm[16448];
  int bid = blockIdx.x, tid = threadIdx.x;
  int wid = tid>>6, lane = tid&63;

  if (bid < nG){
    int jt = bid>>3, c = bid&7;
    for (int i4 = tid; i4 < 1792; i4 += 512){
      int bi = i4/56, kq = i4%56;
      int k = c*224 + kq*4;
      float4 v;
      if (k < 256)      v = *(const float4*)(P.pre + (size_t)(t*32+bi)*256 + k);
      else if (k < 768) v = *(const float4*)(P.ctxP + bi*512 + (k-256));
      else              v = *(const float4*)(P.ahp + bi*1024 + (k-768));
      *(float4*)(sm + bi*224 + kq*4) = v;
    }
    __syncthreads();
    int j0 = jt*128 + lane;
    float acc0[32], acc1[32];
    #pragma unroll
    for (int b=0;b<32;b++){ acc0[b]=0.f; acc1[b]=0.f; }
    int klb = wid*28;
    for (int kt4=0; kt4<7; kt4++){
      int kl = klb + kt4*4;
      size_t kg = (size_t)(c*224 + kl);
      float w00 = (float)P.WATh[(kg+0)*4096+j0], w01 = (float)P.WATh[(kg+1)*4096+j0],
            w02 = (float)P.WATh[(kg+2)*4096+j0], w03 = (float)P.WATh[(kg+3)*4096+j0];
      float w10 = (float)P.WATh[(kg+0)*4096+j0+64], w11 = (float)P.WATh[(kg+1)*4096+j0+64],
            w12 = (float)P.WATh[(kg+2)*4096+j0+64], w13 = (float)P.WATh[(kg+3)*4096+j0+64];
      #pragma unroll
      for (int bq=0; bq<4; bq++){
        float4 xv[8];
        #pragma unroll
        for (int u=0;u<8;u++) xv[u] = *(float4*)(sm + (bq*8+u)*224 + kl);
        #pragma unroll
        for (int u=0;u<8;u++){
          int b = bq*8+u;
          acc0[b] += xv[u].x*w00 + xv[u].y*w01 + xv[u].z*w02 + xv[u].w*w03;
          acc1[b] += xv[u].x*w10 + xv[u].y*w11 + xv[u].z*w12 + xv[u].w*w13;
        }
      }
    }
    __syncthreads();
    #pragma unroll
    for (int b=0;b<32;b++) sm[(wid*32+b)*64 + lane] = acc0[b];
    __syncthreads();
    #pragma unroll
    for (int i=0;i<4;i++){
      int o = tid + i*512; int j2 = o&63, b = o>>6;
      float s = 0.f;
      #pragma unroll
      for (int w2=0;w2<8;w2++) s += sm[(w2*32+b)*64 + j2];
      P.gpA[(size_t)(c*32+b)*4096 + jt*128 + j2] = s;
    }
    __syncthreads();
    #pragma unroll
    for (int b=0;b<32;b++) sm[(wid*32+b)*64 + lane] = acc1[b];
    __syncthreads();
    #pragma unroll
    for (int i=0;i<4;i++){
      int o = tid + i*512; int j2 = o&63, b = o>>6;
      float s = 0.f;
      #pragma unroll
      for (int w2=0;w2<8;w2++) s += sm[(w2*32+b)*64 + j2];
      P.gpA[(size_t)(c*32+b)*4096 + jt*128 + 64 + j2] = s;
    }
  } else if (bid < nG+nConv){
    // location conv (+pm pre-add), fp16 pm/loc
    int gw = (bid-nG)*8 + wid;
    int b = gw>>6, rr = gw&63, t0 = (rr>>1)*16, a = (rr&1)*64 + lane;
    float acc[16];
    #pragma unroll
    for (int tl=0;tl<16;tl++) acc[tl]=0.f;
    #pragma unroll
    for (int c=0;c<2;c++){
      const float* src = c ? P.awc : P.aw;
      float awin[46];
      #pragma unroll
      for (int i=0;i<46;i++){
        int tt = t0-15+i;
        awin[i] = (tt>=0 && tt<512) ? src[b*512+tt] : 0.f;
      }
      #pragma unroll
      for (int k=0;k<31;k++){
        float mcv = P.Mc[(c*31+k)*128 + a];
        #pragma unroll
        for (int tl=0;tl<16;tl++) acc[tl] += awin[tl + k]*mcv;
      }
    }
    #pragma unroll
    for (int tl=0;tl<16;tl++){
      size_t idx = ((size_t)b*512 + t0+tl)*128 + a;
      P.locH[idx] = __float2half(acc[tl] + (float)P.pmH[idx]);
    }
  } else {
    // dec activation for step t-1 (8 partials)
    int b = bid - nG - nConv;
    #pragma unroll
    for (int i=0;i<2;i++){
      int jj = tid + i*512;
      float gi=0.f, gf=0.f, gg=0.f, go=0.f;
      #pragma unroll
      for (int c=0;c<8;c++){
        const float* g = P.gpD + (size_t)(c*32+b)*4096;
        gi += g[jj]; gf += g[1024+jj]; gg += g[2048+jj]; go += g[3072+jj];
      }
      gi += P.bihD[jj]      + P.bhhD[jj];
      gf += P.bihD[1024+jj] + P.bhhD[1024+jj];
      gg += P.bihD[2048+jj] + P.bhhD[2048+jj];
      go += P.bihD[3072+jj] + P.bhhD[3072+jj];
      float c2 = sigf(gf)*P.dc[b*1024+jj] + sigf(gi)*tanhfast(gg);
      float hh = sigf(go)*tanhfast(c2);
      P.dc[b*1024+jj] = c2;
      P.dh[b*1024+jj] = hh;
    }
  }
}

// ---------------- k_BC: att-act + q + scores + softmax + ctx + proj(t-1) ----------------
__global__ __launch_bounds__(512) void k_BC(Ptrs P, int t, int nAtt){
  __shared__ float sm[16448];
  int bid = blockIdx.x, tid = threadIdx.x;
  int wid = tid>>6, lane = tid&63;
  if (bid < nAtt){
    int b = bid;
    #pragma unroll
    for (int i=0;i<2;i++){
      int jj = tid + i*512;
      float gi=0.f, gf=0.f, gg=0.f, go=0.f;
      #pragma unroll
      for (int c=0;c<8;c++){
        const float* g = P.gpA + (size_t)(c*32+b)*4096;
        gi += g[jj]; gf += g[1024+jj]; gg += g[2048+jj]; go += g[3072+jj];
      }
      gi += P.bihA[jj]      + P.bhhA[jj];
      gf += P.bihA[1024+jj] + P.bhhA[1024+jj];
      gg += P.bihA[2048+jj] + P.bhhA[2048+jj];
      go += P.bihA[3072+jj] + P.bhhA[3072+jj];
      float c2 = sigf(gf)*P.acp[b*1024+jj] + sigf(gi)*tanhfast(gg);
      float hh = sigf(go)*tanhfast(c2);
      P.acn[b*1024+jj] = c2;
      P.ahn[b*1024+jj] = hh;
      sm[jj] = hh;
    }
    __syncthreads();
    // q = ah @ Wq^T (fp16 WqT)
    {
      int a = tid&127, kq = tid>>7;
      float p = 0.f;
      for (int k2=0; k2<256; k2+=4){
        int k = kq*256 + k2;
        float4 av = *(float4*)(sm + k);
        p += av.x*(float)P.WqTh[(k+0)*128+a] + av.y*(float)P.WqTh[(k+1)*128+a]
           + av.z*(float)P.WqTh[(k+2)*128+a] + av.w*(float)P.WqTh[(k+3)*128+a];
      }
      sm[1024 + kq*128 + a] = p;
    }
    __syncthreads();
    if (tid < 128) sm[1536+tid] = sm[1024+tid] + sm[1152+tid] + sm[1280+tid] + sm[1408+tid];
    __syncthreads();
    // scores: thread = t-position (fp16 loc)
    int s = tid;
    const __half* lrow = P.locH + ((size_t)b*512 + s)*128;
    float sc = 0.f;
    #pragma unroll
    for (int a=0; a<128; a+=4){
      __half2 h0 = *(const __half2*)(lrow + a);
      __half2 h1 = *(const __half2*)(lrow + a + 2);
      float2 l0 = __half22float2(h0);
      float2 l1 = __half22float2(h1);
      float4 wv = *(const float4*)(P.Wsc + a);
      sc += wv.x*tanhfast(sm[1536+a+0]+l0.x) + wv.y*tanhfast(sm[1536+a+1]+l0.y)
          + wv.z*tanhfast(sm[1536+a+2]+l1.x) + wv.w*tanhfast(sm[1536+a+3]+l1.y);
    }
    float ex = __expf(sc + P.bsc[0]);   // tanh-bounded: safe without max-sub
    float exs = ex;
    #pragma unroll
    for (int d=1; d<64; d<<=1) exs += __shfl_xor(exs, d, 64);
    if (lane==0) sm[2176+wid] = exs;
    __syncthreads();
    float den = sm[2176]+sm[2177]+sm[2178]+sm[2179]+sm[2180]+sm[2181]+sm[2182]+sm[2183];
    float w = ex / den;
    P.aw[b*512+s] = w;
    P.awc[b*512+s] += w;
    P.out[ALIGN_OFF + (size_t)b*204800 + (size_t)t*512 + s] = w;
    sm[1664+s] = w;
    __syncthreads();
    // ctx = w · memory (fp16 memH), thread = e
    int e = tid;
    float acc = 0.f;
    for (int t2=0; t2<512; t2+=4){
      float4 wv = *(float4*)(sm + 1664 + t2);
      const __half* mr = P.memH + ((size_t)b*512 + t2)*512 + e;
      acc += wv.x*(float)mr[0] + wv.y*(float)mr[512] + wv.z*(float)mr[1024] + wv.w*(float)mr[1536];
    }
    P.ctxN[b*512+e] = acc;
  } else {
    // projection for step t-1 (fp32): x = [dh(1024) | ctxP(512)]
    int eb = bid - nAtt;
    int b0 = (eb&1)*16;
    int row = (eb>>1)*8 + wid;
    bool act = (row <= 80);
    const float* wrow = (row<80) ? (P.Wproj + (size_t)row*1536) : P.Wgate;
    float acc[16];
    #pragma unroll
    for (int bi=0;bi<16;bi++) acc[bi]=0.f;
    for (int i4=tid; i4<4096; i4+=512){
      int bi=i4>>8, kk=(i4&255)<<2;
      *(float4*)(sm + bi*1024 + kk) = *(const float4*)(P.dh + (b0+bi)*1024 + kk);
    }
    __syncthreads();
    if (act){
      #pragma unroll
      for (int kq=0;kq<4;kq++){
        int k0=kq*256+lane*4;
        float4 w4 = *(const float4*)(wrow + k0);
        #pragma unroll
        for (int bi=0;bi<16;bi++){
          float4 x = *(float4*)(sm + bi*1024 + k0);
          acc[bi] += x.x*w4.x + x.y*w4.y + x.z*w4.z + x.w*w4.w;
        }
      }
    }
    __syncthreads();
    for (int i4=tid; i4<2048; i4+=512){
      int bi=i4>>7, kk=(i4&127)<<2;
      *(float4*)(sm + bi*512 + kk) = *(const float4*)(P.ctxP + (b0+bi)*512 + kk);
    }
    __syncthreads();
    if (act){
      #pragma unroll
      for (int kq=0;kq<2;kq++){
        int k0=kq*256+lane*4;
        float4 w4 = *(const float4*)(wrow + 1024 + k0);
        #pragma unroll
        for (int bi=0;bi<16;bi++){
          float4 x = *(float4*)(sm + bi*512 + k0);
          acc[bi] += x.x*w4.x + x.y*w4.y + x.z*w4.z + x.w*w4.w;
        }
      }
      #pragma unroll
      for (int bi=0;bi<16;bi++){
        float v = acc[bi];
        #pragma unroll
        for (int d=1; d<64; d<<=1) v += __shfl_xor(v, d, 64);
        acc[bi]=v;
      }
      if (lane==0){
        float bias = (row<80)? P.bproj[row] : P.bgate[0];
        #pragma unroll
        for (int bi=0;bi<16;bi++){
          float v = acc[bi]+bias;
          if (row<80) P.out[(size_t)(b0+bi)*32000 + row*400 + (t-1)] = v;
          else        P.out[GATE_OFF + (b0+bi)*400 + (t-1)] = v;
        }
      }
    }
  }
}

// ---------------- k_D: dec-GEMM (LDS-staged, jr=2, fp16 W): K=2560 ----------------
__global__ __launch_bounds__(512, 4) void k_D(Ptrs P){
  __shared__ float sm[16448];
  int bid = blockIdx.x, tid = threadIdx.x;
  int wid = tid>>6, lane = tid&63;
  int jt = bid>>3, c = bid&7;
  for (int i4 = tid; i4 < 2560; i4 += 512){
    int bi = i4/80, kq = i4%80;
    int k = c*320 + kq*4;
    float4 v;
    if (k < 1024)      v = *(const float4*)(P.ahn + bi*1024 + k);
    else if (k < 1536) v = *(const float4*)(P.ctxN + bi*512 + (k-1024));
    else               v = *(const float4*)(P.dh + bi*1024 + (k-1536));
    *(float4*)(sm + bi*320 + kq*4) = v;
  }
  __syncthreads();
  int j0 = jt*128 + lane;
  float acc0[32], acc1[32];
  #pragma unroll
  for (int b=0;b<32;b++){ acc0[b]=0.f; acc1[b]=0.f; }
  int klb = wid*40;
  for (int kt4=0; kt4<10; kt4++){
    int kl = klb + kt4*4;
    size_t kg = (size_t)(c*320 + kl);
    float w00 = (float)P.WDTh[(kg+0)*4096+j0], w01 = (float)P.WDTh[(kg+1)*4096+j0],
          w02 = (float)P.WDTh[(kg+2)*4096+j0], w03 = (float)P.WDTh[(kg+3)*4096+j0];
    float w10 = (float)P.WDTh[(kg+0)*4096+j0+64], w11 = (float)P.WDTh[(kg+1)*4096+j0+64],
          w12 = (float)P.WDTh[(kg+2)*4096+j0+64], w13 = (float)P.WDTh[(kg+3)*4096+j0+64];
    #pragma unroll
    for (int bq=0; bq<4; bq++){
      float4 xv[8];
      #pragma unroll
      for (int u=0;u<8;u++) xv[u] = *(float4*)(sm + (bq*8+u)*320 + kl);
      #pragma unroll
      for (int u=0;u<8;u++){
        int b = bq*8+u;
        acc0[b] += xv[u].x*w00 + xv[u].y*w01 + xv[u].z*w02 + xv[u].w*w03;
        acc1[b] += xv[u].x*w10 + xv[u].y*w11 + xv[u].z*w12 + xv[u].w*w13;
      }
    }
  }
  __syncthreads();
  #pragma unroll
  for (int b=0;b<32;b++) sm[(wid*32+b)*64 + lane] = acc0[b];
  __syncthreads();
  #pragma unroll
  for (int i=0;i<4;i++){
    int o = tid + i*512; int j2 = o&63, b = o>>6;
    float s = 0.f;
    #pragma unroll
    for (int w2=0;w2<8;w2++) s += sm[(w2*32+b)*64 + j2];
    P.gpD[(size_t)(c*32+b)*4096 + jt*128 + j2] = s;
  }
  __syncthreads();
  #pragma unroll
  for (int b=0;b<32;b++) sm[(wid*32+b)*64 + lane] = acc1[b];
  __syncthreads();
  #pragma unroll
  for (int i=0;i<4;i++){
    int o = tid + i*512; int j2 = o&63, b = o>>6;
    float s = 0.f;
    #pragma unroll
    for (int w2=0;w2<8;w2++) s += sm[(w2*32+b)*64 + j2];
    P.gpD[(size_t)(c*32+b)*4096 + jt*128 + 64 + j2] = s;
  }
}

// ---------------- host ----------------
extern "C" void kernel_launch(void* const* d_in, const int* in_sizes, int n_in,
                              void* d_out, int out_size, void* d_ws, size_t ws_size,
                              hipStream_t stream) {
  Ptrs P;
  P.mem   = (const float*)d_in[0];  P.dec   = (const float*)d_in[1];
  P.Wpre1 = (const float*)d_in[2];  P.Wpre2 = (const float*)d_in[3];
  P.WihA  = (const float*)d_in[4];  P.WhhA  = (const float*)d_in[5];
  P.bihA  = (const float*)d_in[6];  P.bhhA  = (const float*)d_in[7];
  P.WihD  = (const float*)d_in[8];  P.WhhD  = (const float*)d_in[9];
  P.bihD  = (const float*)d_in[10]; P.bhhD  = (const float*)d_in[11];
  P.Wq    = (const float*)d_in[12]; P.Wm    = (const float*)d_in[13];
  P.Wsc   = (const float*)d_in[14]; P.bsc   = (const float*)d_in[15];
  P.Wlc   = (const float*)d_in[16]; P.Wld   = (const float*)d_in[17];
  P.Wproj = (const float*)d_in[18]; P.bproj = (const float*)d_in[19];
  P.Wgate = (const float*)d_in[20]; P.bgate = (const float*)d_in[21];
  P.out = (float*)d_out;

  float* ws = (float*)d_ws;
  size_t o = 0;
  P.pmH  = (__half*)(ws + o); o += 1048576;   // [32][512][128] fp16
  P.pre  = ws + o; o += 3276800;
  P.locH = (__half*)(ws + o); o += 1048576;   // fp16
  P.WqTh = (__half*)(ws + o); o += 65536;     // fp16 [1024][128]
  P.Mc   = ws + o; o += 8192;
  P.W1T  = ws + o; o += 20480;
  P.W2T  = ws + o; o += 65536;
  P.WmT  = ws + o; o += 65536;
  P.gpA  = ws + o; o += 1048576;              // [8][32][4096] fp32
  P.gpD  = ws + o; o += 1048576;
  float* stateBase = ws + o;
  float* AH[2]; AH[0] = ws + o; o += 32768; AH[1] = ws + o; o += 32768;
  float* AC[2]; AC[0] = ws + o; o += 32768; AC[1] = ws + o; o += 32768;
  P.dh  = ws + o; o += 32768;
  P.dc  = ws + o; o += 32768;
  float* CT[2]; CT[0] = ws + o; o += 16384; CT[1] = ws + o; o += 16384;
  P.aw  = ws + o; o += 16384;
  P.awc = ws + o; o += 16384;
  int stateN = (int)((ws + o) - stateBase);
  P.memH = (__half*)(ws + o); o += 4194304;   // [32][512][512] fp16
  P.WATh = (__half*)(ws + o); o += 3670016;   // [1792][4096] fp16
  P.WDTh = (__half*)(ws + o); o += 5242880;   // [2560][4096] fp16
  P.p1   = (float*)P.WATh;                    // prologue scratch aliases WATh region

  P.ahp = AH[0]; P.ahn = AH[1]; P.acp = AC[0]; P.acn = AC[1];
  P.ctxP = CT[0]; P.ctxN = CT[1];

  hipLaunchKernelGGL(k_init, dim3((stateN+255)/256), dim3(256), 0, stream, stateBase, stateN);
  hipLaunchKernelGGL(k_memh, dim3(8192), dim3(1024), 0, stream, P);
  hipLaunchKernelGGL(k_xform, dim3(1135), dim3(256), 0, stream, P);
  hipLaunchKernelGGL(k_pn1, dim3(1600), dim3(256), 0, stream, P);
  hipLaunchKernelGGL(k_pn2, dim3(1600), dim3(256), 0, stream, P);
  hipLaunchKernelGGL(k_pm,  dim3(2048), dim3(256), 0, stream, P);
  hipLaunchKernelGGL(k_tA,  dim3(128*56), dim3(256), 0, stream, P);
  hipLaunchKernelGGL(k_tD,  dim3(128*80), dim3(256), 0, stream, P);

  for (int t=0; t<400; t++){
    Ptrs Q = P;
    Q.ahp = AH[t&1];     Q.ahn = AH[(t+1)&1];
    Q.acp = AC[t&1];     Q.acn = AC[(t+1)&1];
    Q.ctxP = CT[t&1];    Q.ctxN = CT[(t+1)&1];
    int nActD = t ? 32 : 0;
    int nProj = t ? 22 : 0;
    hipLaunchKernelGGL(k_A, dim3(512+nActD), dim3(512), 0, stream, Q, t, 256, 256, nActD);
    hipLaunchKernelGGL(k_BC, dim3(32+nProj), dim3(512), 0, stream, Q, t, 32);
    hipLaunchKernelGGL(k_D, dim3(256), dim3(512), 0, stream, Q);
  }
  // tail: dec activation for t=399, then projection for t=399
  Ptrs Q = P;
  Q.ahp = AH[0]; Q.ahn = AH[1]; Q.acp = AC[0]; Q.acn = AC[1];
  Q.ctxP = CT[0]; Q.ctxN = CT[1];   // ctx_399 lives in CT[0]
  hipLaunchKernelGGL(k_A, dim3(32), dim3(512), 0, stream, Q, 400, 0, 0, 32);
  hipLaunchKernelGGL(k_BC, dim3(22), dim3(512), 0, stream, Q, 400, 0);
}